// Round 4
// baseline (285.768 us; speedup 1.0000x reference)
//
#include <hip/hip_runtime.h>

typedef __bf16 bf16x8 __attribute__((ext_vector_type(8)));
typedef float  f32x4  __attribute__((ext_vector_type(4)));
typedef float  f32x16 __attribute__((ext_vector_type(16)));
typedef float  f32x2  __attribute__((ext_vector_type(2)));
typedef unsigned int uint32;
typedef unsigned int u32x4 __attribute__((ext_vector_type(4)));
typedef unsigned int u32x2 __attribute__((ext_vector_type(2)));

#define MFMA16(a, b, c) __builtin_amdgcn_mfma_f32_16x16x32_bf16((a), (b), (c), 0, 0, 0)
#define MFMA32(a, b, c) __builtin_amdgcn_mfma_f32_32x32x16_bf16((a), (b), (c), 0, 0, 0)
// global -> LDS direct DMA, 16B per lane; dest = wave-uniform base + lane*16
#define GLL(gsrc, ldst) __builtin_amdgcn_global_load_lds( \
    (const __attribute__((address_space(1))) uint32*)(gsrc), \
    (__attribute__((address_space(3))) uint32*)(ldst), 16, 0, 0)

static constexpr int Cch = 128;   // channels
static constexpr int Nvox = 8192; // D*H*W = 8*32*32

__device__ inline unsigned int pkbf(float x, float y) {
  unsigned short ux = __builtin_bit_cast(unsigned short, (__bf16)x);
  unsigned short uy = __builtin_bit_cast(unsigned short, (__bf16)y);
  return (unsigned int)ux | ((unsigned int)uy << 16);
}
__device__ inline float bflo(unsigned int u) {
  return __builtin_bit_cast(float, u << 16);
}
__device__ inline float bfhi(unsigned int u) {
  return __builtin_bit_cast(float, u & 0xffff0000u);
}

// ---------------- K1a: GroupNorm partial sums: 256 blocks -------------------
__global__ __launch_bounds__(256) void gn_part_k(const float* __restrict__ x,
                                                 f32x2* __restrict__ part) {
  int bg = blockIdx.x >> 4, pt = blockIdx.x & 15;
  const f32x4* xb = (const f32x4*)(x + (size_t)bg * 131072 + (size_t)pt * 8192);
  float s = 0.f, ss = 0.f;
  for (int i = threadIdx.x; i < 2048; i += 256) {
    f32x4 v = xb[i];
    s += (v.x + v.y) + (v.z + v.w);
    ss += (v.x * v.x + v.y * v.y) + (v.z * v.z + v.w * v.w);
  }
#pragma unroll
  for (int off = 32; off; off >>= 1) {
    s  += __shfl_down(s, off);
    ss += __shfl_down(ss, off);
  }
  __shared__ float rb[4], rbss[4];
  if ((threadIdx.x & 63) == 0) { rb[threadIdx.x >> 6] = s; rbss[threadIdx.x >> 6] = ss; }
  __syncthreads();
  if (threadIdx.x == 0) {
    f32x2 o; o.x = rb[0] + rb[1] + rb[2] + rb[3];
    o.y = rbss[0] + rbss[1] + rbss[2] + rbss[3];
    part[blockIdx.x] = o;
  }
}

// ---------------- K1b: GroupNorm finish: 1 block ----------------------------
__global__ __launch_bounds__(256) void gn_fin_k(const f32x2* __restrict__ part,
                                                float* __restrict__ stats) {
  int tid = threadIdx.x;
  f32x2 v = part[tid];
  float s = v.x, ss = v.y;
#pragma unroll
  for (int off = 1; off < 16; off <<= 1) {
    s += __shfl_xor(s, off);
    ss += __shfl_xor(ss, off);
  }
  if ((tid & 15) == 0) {
    int bg = tid >> 4;
    const float invn = 1.f / 131072.f;
    float mean = s * invn;
    float var = ss * invn - mean * mean;
    stats[bg] = mean;
    stats[16 + bg] = rsqrtf(var + 1e-5f);
  }
}

// ---------------- K2: weight f32 -> bf16 ----------------
__global__ __launch_bounds__(256) void conv_w_k(const float* __restrict__ wq,
                                                const float* __restrict__ wp,
                                                __bf16* __restrict__ wqb,
                                                __bf16* __restrict__ wpb) {
  int i = blockIdx.x * 256 + threadIdx.x;
  if (i < 384 * 128) wqb[i] = (__bf16)wq[i];
  if (i < 128 * 128) wpb[i] = (__bf16)wp[i];
}

// ---------------- K3: normalize + transpose to xn[b][n][c] (bf16) ------------
__global__ __launch_bounds__(256) void gn_apply_k(const float* __restrict__ x,
                                                  const float* __restrict__ gamma,
                                                  const float* __restrict__ beta,
                                                  const float* __restrict__ stats,
                                                  __bf16* __restrict__ xn) {
  __shared__ __bf16 t[64][136];
  int b = blockIdx.x >> 7;
  int n0 = (blockIdx.x & 127) << 6;
  const float* xb = x + (size_t)b * Cch * Nvox;
  for (int i = threadIdx.x; i < 128 * 64; i += 256) {
    int c = i >> 6, nl = i & 63;
    int g = c >> 4;
    float mean = stats[b * 8 + g];
    float rstd = stats[16 + b * 8 + g];
    float v = xb[(size_t)c * Nvox + n0 + nl];
    t[nl][c] = (__bf16)((v - mean) * rstd * gamma[c] + beta[c]);
  }
  __syncthreads();
  __bf16* outb = xn + (size_t)b * Nvox * Cch;
  for (int i = threadIdx.x; i < 64 * 16; i += 256) {
    int row = i >> 4, ch = (i & 15) << 3;
    *reinterpret_cast<bf16x8*>(&outb[(size_t)(n0 + row) * Cch + ch]) =
        *reinterpret_cast<const bf16x8*>(&t[row][ch]);
  }
}

// ---------------- K4: QKV GEMM (MFMA bf16) -----------------------------------
__global__ __launch_bounds__(256) void qkv_k(const __bf16* __restrict__ xn,
                                             const __bf16* __restrict__ wq,
                                             const float* __restrict__ b_qkv,
                                             __bf16* __restrict__ q,
                                             __bf16* __restrict__ k,
                                             __bf16* __restrict__ vt) {
  int id = blockIdx.x;               // 2 * 6 * 128 blocks
  int b = id / 768;
  int rr = id % 768;
  int o0 = (rr >> 7) * 64;
  int n0 = (rr & 127) * 64;
  int w = threadIdx.x >> 6, l = threadIdx.x & 63;
  int lr = l & 15, lh = l >> 4;
  int ow = o0 + w * 16;

  bf16x8 a[4];
#pragma unroll
  for (int kc = 0; kc < 4; kc++)
    a[kc] = *reinterpret_cast<const bf16x8*>(&wq[(size_t)(ow + lr) * 128 + kc * 32 + lh * 8]);

  const __bf16* xb = xn + (size_t)b * Nvox * Cch;
#pragma unroll
  for (int ns = 0; ns < 4; ns++) {
    f32x4 acc = {0.f, 0.f, 0.f, 0.f};
#pragma unroll
    for (int kc = 0; kc < 4; kc++) {
      bf16x8 bf = *reinterpret_cast<const bf16x8*>(
          &xb[(size_t)(n0 + ns * 16 + lr) * Cch + kc * 32 + lh * 8]);
      acc = MFMA16(a[kc], bf, acc);
    }
#pragma unroll
    for (int r2 = 0; r2 < 4; r2++) {
      int o = ow + lh * 4 + r2;
      int n = n0 + ns * 16 + lr;
      float val = acc[r2] + b_qkv[o];
      if (o < 128)
        q[((size_t)b * Nvox + n) * Cch + o] = (__bf16)val;
      else if (o < 256)
        k[((size_t)b * Nvox + n) * Cch + (o - 128)] = (__bf16)val;
      else
        vt[((size_t)b * Cch + (o - 256)) * Nvox + n] = (__bf16)val;
    }
  }
}

// ---------------- K5: flash attention v4 -------------------------------------
// 256 blocks = kq(4) x b(2) x qgrp(32). 8 warps = 4 q-tiles (q=64 each,
// QBLK=256) x 2 k-subhalves g. Block covers k-quarter (2048 rows) in 16 iters
// of KVBLK=128; one staged tile serves all 8 warps. In-block merge of the 2
// k-subhalves (bf16 LDS); 4 global partials merged by merge4_k.
// blockIdx low bits = (b*4+kq) -> each XCD owns one (b,kq) KV slice (L2-fit).
__global__ __launch_bounds__(512, 2) void attn_k(const __bf16* __restrict__ q,
                                                 const __bf16* __restrict__ kk,
                                                 const __bf16* __restrict__ vt,
                                                 __bf16* __restrict__ po0,
                                                 __bf16* __restrict__ po1,
                                                 __bf16* __restrict__ po2,
                                                 __bf16* __restrict__ po3,
                                                 f32x2* __restrict__ ml) {
  extern __shared__ char smem[];   // 128KB: K[2][32K] | V[2][32K]
  const int bi = blockIdx.x;
  const int kq = bi & 3;
  const int b = (bi >> 2) & 1;
  const int qgrp = bi >> 3;            // 0..31
  const int w = threadIdx.x >> 6;      // 0..7
  const int l = threadIdx.x & 63;
  const int l31 = l & 31, h = l >> 5;
  const int g = w >> 2, wqt = w & 3;   // k-subhalf, q-tile
  const int sw = (l & 7) << 4;         // read-side XOR swizzle

  const char* kbase = (const char*)kk + ((size_t)b * 8192 + (size_t)kq * 2048) * 256;
  const char* vbase = (const char*)vt + (size_t)b * 2097152 + (size_t)kq * 4096;

  // Q B-fragments in registers: col q = l31, k-elems h*8..+8
  const __bf16* qptr = q + ((size_t)b * 8192 + (size_t)qgrp * 256 + (size_t)wqt * 64) * 128;
  bf16x8 qa[2][8];
#pragma unroll
  for (int sq = 0; sq < 2; sq++)
#pragma unroll
    for (int dc = 0; dc < 8; dc++)
      qa[sq][dc] = *reinterpret_cast<const bf16x8*>(
          &qptr[(size_t)(sq * 32 + l31) * 128 + dc * 16 + h * 8]);

  f32x16 O[4][2];
#pragma unroll
  for (int cb = 0; cb < 4; cb++)
#pragma unroll
    for (int sq = 0; sq < 2; sq++)
#pragma unroll
      for (int r = 0; r < 16; r++) O[cb][sq][r] = 0.f;
  float msc[2] = {-1e30f, -1e30f};
  float lsum[2] = {0.f, 0.f};

  const float k2 = 0.08838834764831845f * 1.4426950408889634f; // scale*log2e

  // stage one 128-row K/V tile: warps 0-3 K (8KB each), warps 4-7 V (8KB each)
  auto stage = [&](int t, int bs) {
    int c0 = (w & 3) * 8;
    if (w < 4) {
      const char* kt = kbase + (size_t)t * 32768;
      char* dst = smem + bs * 32768;
#pragma unroll
      for (int it = 0; it < 8; ++it) {
        int o = (c0 + it) * 1024 + l * 16;
        int row = o >> 8, col = (o & 255) ^ ((row & 7) << 4);
        GLL(kt + (size_t)row * 256 + col, dst + (c0 + it) * 1024);
      }
    } else {
      const char* vtt = vbase + (size_t)t * 256;
      char* dst = smem + 65536 + bs * 32768;
#pragma unroll
      for (int it = 0; it < 8; ++it) {
        int o = (c0 + it) * 1024 + l * 16;
        int row = o >> 8, col = (o & 255) ^ ((row & 7) << 4);
        GLL(vtt + (size_t)row * 16384 + col, dst + (c0 + it) * 1024);
      }
    }
  };

  stage(0, 0);
  int cur = 0;
  const int NT = 16;

  for (int t = 0; t < NT; ++t) {
    __syncthreads();                   // buf[cur] staged (vmcnt drained)
    if (t + 1 < NT) stage(t + 1, cur ^ 1);

    const char* Kb = smem + cur * 32768;
    const char* Vb = smem + 65536 + cur * 32768;

    // ---- QK^T (swapped): St[ks][sq], rows=k, cols=q -----------------------
    f32x16 St[2][2];
#pragma unroll
    for (int ks = 0; ks < 2; ks++)
#pragma unroll
      for (int sq = 0; sq < 2; sq++)
#pragma unroll
        for (int r = 0; r < 16; r++) St[ks][sq][r] = 0.f;
#pragma unroll
    for (int ks = 0; ks < 2; ks++) {
      int krow = g * 64 + ks * 32 + l31;
#pragma unroll
      for (int dc = 0; dc < 8; dc++) {
        bf16x8 kf = *reinterpret_cast<const bf16x8*>(
            Kb + (size_t)krow * 256 + ((dc * 32 + h * 16) ^ sw));
#pragma unroll
        for (int sq = 0; sq < 2; sq++)
          St[ks][sq] = MFMA32(kf, qa[sq][dc], St[ks][sq]);
      }
    }

    // ---- online softmax (per q = lane col) + in-register P packing --------
    u32x4 pk[2][2][2];  // [sq][ks][kc]
#pragma unroll
    for (int sq = 0; sq < 2; sq++) {
      // tree max over the 32 in-lane values
      f32x16 mm;
#pragma unroll
      for (int r = 0; r < 16; r++) mm[r] = fmaxf(St[0][sq][r], St[1][sq][r]);
#pragma unroll
      for (int st = 8; st; st >>= 1)
#pragma unroll
        for (int r = 0; r < 8; r++)
          if (r < st) mm[r] = fmaxf(mm[r], mm[r + st]);
      float pm = fmaxf(mm[0], __shfl_xor(mm[0], 32));
      float pms = pm * k2;
      if (__any(pms > msc[sq] + 8.f)) {   // defer-max (T13)
        float nm = fmaxf(msc[sq], pms);
        float al = __builtin_amdgcn_exp2f(msc[sq] - nm);
        msc[sq] = nm;
        lsum[sq] *= al;
#pragma unroll
        for (int cb = 0; cb < 4; cb++)
#pragma unroll
          for (int r = 0; r < 16; r++) O[cb][sq][r] *= al;
      }
      float p[2][16];
#pragma unroll
      for (int ks = 0; ks < 2; ks++)
#pragma unroll
        for (int r = 0; r < 16; r++)
          p[ks][r] = __builtin_amdgcn_exp2f(St[ks][sq][r] * k2 - msc[sq]);
      // tree sum
      f32x16 sm;
#pragma unroll
      for (int r = 0; r < 16; r++) sm[r] = p[0][r] + p[1][r];
#pragma unroll
      for (int st = 8; st; st >>= 1)
#pragma unroll
        for (int r = 0; r < 8; r++)
          if (r < st) sm[r] = sm[r] + sm[r + st];
      float rs = sm[0] + __shfl_xor(sm[0], 32);
      lsum[sq] += rs;
      // pack to PV B-frags
#pragma unroll
      for (int ks = 0; ks < 2; ks++) {
#pragma unroll
        for (int kc = 0; kc < 2; kc++) {
          int bs = kc * 8;
          unsigned int a0 = pkbf(p[ks][bs + 0], p[ks][bs + 1]);
          unsigned int a1 = pkbf(p[ks][bs + 2], p[ks][bs + 3]);
          unsigned int b0 = pkbf(p[ks][bs + 4], p[ks][bs + 5]);
          unsigned int b1 = pkbf(p[ks][bs + 6], p[ks][bs + 7]);
          unsigned int sa0 = __shfl_xor(a0, 32), sa1 = __shfl_xor(a1, 32);
          unsigned int sb0 = __shfl_xor(b0, 32), sb1 = __shfl_xor(b1, 32);
          bool lo = (l < 32);
          u32x4 pv;
          pv[0] = lo ? a0 : sb0;
          pv[1] = lo ? a1 : sb1;
          pv[2] = lo ? sa0 : b0;
          pv[3] = lo ? sa1 : b1;
          pk[sq][ks][kc] = pv;
        }
      }
    }

    // ---- PV: O^T[c][q] += V^T-frag x P-frag --------------------------------
#pragma unroll
    for (int ks = 0; ks < 2; ks++) {
#pragma unroll
      for (int kc = 0; kc < 2; kc++) {
#pragma unroll
        for (int cb = 0; cb < 4; cb++) {
          bf16x8 vf = *reinterpret_cast<const bf16x8*>(
              Vb + (size_t)(cb * 32 + l31) * 256 +
              ((g * 128 + ks * 64 + kc * 32 + h * 16) ^ sw));
#pragma unroll
          for (int sq = 0; sq < 2; sq++)
            O[cb][sq] = MFMA32(vf, __builtin_bit_cast(bf16x8, pk[sq][ks][kc]),
                               O[cb][sq]);
        }
      }
    }
    cur ^= 1;
  }

  // ---- in-block merge of the two k-subhalves (bf16 via LDS) ----------------
  __syncthreads();                    // tile bufs dead; reuse for merge
  char* mO = smem;                    // 16 chunks x 256 slots x 16B = 64KB
  float* mlb = (float*)(smem + 65536); // [4 wq][32 q][2 sq][2]
  if (g == 1) {
#pragma unroll
    for (int cb = 0; cb < 4; cb++)
#pragma unroll
      for (int sq = 0; sq < 2; sq++)
#pragma unroll
        for (int hf = 0; hf < 2; hf++) {
          int j = (cb * 2 + sq) * 2 + hf;
          u32x4 pv;
#pragma unroll
          for (int i = 0; i < 4; i++)
            pv[i] = pkbf(O[cb][sq][hf * 8 + 2 * i], O[cb][sq][hf * 8 + 2 * i + 1]);
          *reinterpret_cast<u32x4*>(mO + ((size_t)j * 256 + wqt * 64 + l) * 16) = pv;
        }
    if (l < 32) {
#pragma unroll
      for (int sq = 0; sq < 2; sq++) {
        mlb[((wqt * 32 + l31) * 2 + sq) * 2 + 0] = msc[sq];
        mlb[((wqt * 32 + l31) * 2 + sq) * 2 + 1] = lsum[sq];
      }
    }
  }
  __syncthreads();
  if (g == 0) {
    __bf16* po = (kq == 0) ? po0 : (kq == 1) ? po1 : (kq == 2) ? po2 : po3;
#pragma unroll
    for (int sq = 0; sq < 2; sq++) {
      float m2 = mlb[((wqt * 32 + l31) * 2 + sq) * 2 + 0];
      float l2 = mlb[((wqt * 32 + l31) * 2 + sq) * 2 + 1];
      float M = fmaxf(msc[sq], m2);
      float e1 = __builtin_amdgcn_exp2f(msc[sq] - M);
      float e2 = __builtin_amdgcn_exp2f(m2 - M);
      lsum[sq] = e1 * lsum[sq] + e2 * l2;
      msc[sq] = M;
#pragma unroll
      for (int cb = 0; cb < 4; cb++)
#pragma unroll
        for (int hf = 0; hf < 2; hf++) {
          int j = (cb * 2 + sq) * 2 + hf;
          u32x4 pv = *reinterpret_cast<const u32x4*>(
              mO + ((size_t)j * 256 + wqt * 64 + l) * 16);
#pragma unroll
          for (int i = 0; i < 4; i++) {
            O[cb][sq][hf * 8 + 2 * i] =
                e1 * O[cb][sq][hf * 8 + 2 * i] + e2 * bflo(pv[i]);
            O[cb][sq][hf * 8 + 2 * i + 1] =
                e1 * O[cb][sq][hf * 8 + 2 * i + 1] + e2 * bfhi(pv[i]);
          }
        }
      // write unnormalized partial O^T (bf16) + (m, l)
      int qg = b * 8192 + qgrp * 256 + wqt * 64 + sq * 32 + l31;
#pragma unroll
      for (int cb = 0; cb < 4; cb++) {
#pragma unroll
        for (int rq = 0; rq < 4; rq++) {
          int c = cb * 32 + rq * 8 + h * 4;
          u32x2 wv;
          wv[0] = pkbf(O[cb][sq][rq * 4 + 0], O[cb][sq][rq * 4 + 1]);
          wv[1] = pkbf(O[cb][sq][rq * 4 + 2], O[cb][sq][rq * 4 + 3]);
          *reinterpret_cast<u32x2*>((char*)po + ((size_t)qg * 128 + c) * 2) = wv;
        }
      }
      if (l < 32) {
        f32x2 v; v.x = msc[sq]; v.y = lsum[sq];
        ml[(size_t)kq * 16384 + qg] = v;
      }
    }
  }
}

// ---------------- K5b: merge the four k-quarters -----------------------------
__global__ __launch_bounds__(256) void merge4_k(__bf16* __restrict__ po0,
                                                const __bf16* __restrict__ po1,
                                                const __bf16* __restrict__ po2,
                                                const __bf16* __restrict__ po3,
                                                const f32x2* __restrict__ ml) {
  int t = blockIdx.x * 256 + threadIdx.x;   // 65536 threads
  int qg = t >> 2;
  int c0 = (t & 3) * 32;
  f32x2 a0 = ml[qg], a1 = ml[16384 + qg], a2 = ml[32768 + qg], a3 = ml[49152 + qg];
  float M = fmaxf(fmaxf(a0.x, a1.x), fmaxf(a2.x, a3.x));
  float e0 = __builtin_amdgcn_exp2f(a0.x - M);
  float e1 = __builtin_amdgcn_exp2f(a1.x - M);
  float e2 = __builtin_amdgcn_exp2f(a2.x - M);
  float e3 = __builtin_amdgcn_exp2f(a3.x - M);
  float L = e0 * a0.y + e1 * a1.y + e2 * a2.y + e3 * a3.y;
  float invL = 1.f / L;
  float c0f = e0 * invL, c1f = e1 * invL, c2f = e2 * invL, c3f = e3 * invL;
#pragma unroll
  for (int j = 0; j < 4; j++) {
    size_t off = (size_t)qg * 128 + c0 + j * 8;
    bf16x8 v0 = *reinterpret_cast<const bf16x8*>(&po0[off]);
    bf16x8 v1 = *reinterpret_cast<const bf16x8*>(&po1[off]);
    bf16x8 v2 = *reinterpret_cast<const bf16x8*>(&po2[off]);
    bf16x8 v3 = *reinterpret_cast<const bf16x8*>(&po3[off]);
    bf16x8 o;
#pragma unroll
    for (int i = 0; i < 8; i++)
      o[i] = (__bf16)(c0f * (float)v0[i] + c1f * (float)v1[i] +
                      c2f * (float)v2[i] + c3f * (float)v3[i]);
    *reinterpret_cast<bf16x8*>(&po0[off]) = o;
  }
}

// ---------------- K6: proj GEMM + bias + residual ----------------------------
__global__ __launch_bounds__(256) void proj_k(const __bf16* __restrict__ h,
                                              const __bf16* __restrict__ wp,
                                              const float* __restrict__ b_proj,
                                              const float* __restrict__ x,
                                              float* __restrict__ out) {
  int id = blockIdx.x;            // 2 * 2 * 128
  int b = id >> 8;
  int co0 = ((id >> 7) & 1) * 64;
  int n0 = (id & 127) * 64;
  int w = threadIdx.x >> 6, l = threadIdx.x & 63;
  int lr = l & 15, lh = l >> 4;
  int cow = co0 + w * 16;

  bf16x8 a[4];
#pragma unroll
  for (int kc = 0; kc < 4; kc++)
    a[kc] = *reinterpret_cast<const bf16x8*>(&wp[(size_t)(cow + lr) * 128 + kc * 32 + lh * 8]);

  const __bf16* hb = h + (size_t)b * Nvox * Cch;
#pragma unroll
  for (int ns = 0; ns < 4; ns++) {
    f32x4 acc = {0.f, 0.f, 0.f, 0.f};
#pragma unroll
    for (int kc = 0; kc < 4; kc++) {
      bf16x8 bf = *reinterpret_cast<const bf16x8*>(
          &hb[(size_t)(n0 + ns * 16 + lr) * Cch + kc * 32 + lh * 8]);
      acc = MFMA16(a[kc], bf, acc);
    }
#pragma unroll
    for (int r2 = 0; r2 < 4; r2++) {
      int co = cow + lh * 4 + r2;
      int n = n0 + ns * 16 + lr;
      size_t idx = ((size_t)b * Cch + co) * Nvox + n;
      out[idx] = x[idx] + b_proj[co] + acc[r2];
    }
  }
}

extern "C" void kernel_launch(void* const* d_in, const int* in_sizes, int n_in,
                              void* d_out, int out_size, void* d_ws, size_t ws_size,
                              hipStream_t stream) {
  const float* x      = (const float*)d_in[0];
  const float* gamma  = (const float*)d_in[1];
  const float* beta   = (const float*)d_in[2];
  const float* w_qkv  = (const float*)d_in[3];
  const float* b_qkv  = (const float*)d_in[4];
  const float* w_proj = (const float*)d_in[5];
  const float* b_proj = (const float*)d_in[6];
  float* out = (float*)d_out;

  char* ws = (char*)d_ws;
  float*  stats = (float*)ws;                      // 128 B
  f32x2*  part  = (f32x2*)(ws + 256);              // 2 KB
  __bf16* wq_b  = (__bf16*)(ws + 4096);            // 98304 B
  __bf16* wp_b  = (__bf16*)(ws + 4096 + 98304);    // 32768 B
  size_t base = 135168;
  const size_t SZ = (size_t)2 * Nvox * Cch * sizeof(__bf16); // 4 MiB
  __bf16* xn  = (__bf16*)(ws + base + 0 * SZ);     // reused as po1
  __bf16* qw  = (__bf16*)(ws + base + 1 * SZ);
  __bf16* kw  = (__bf16*)(ws + base + 2 * SZ);
  __bf16* vtw = (__bf16*)(ws + base + 3 * SZ);
  __bf16* hw  = (__bf16*)(ws + base + 4 * SZ);     // po0, then merged h
  f32x2*  ml  = (f32x2*)(ws + base + 5 * SZ);      // 512 KB
  __bf16* po2 = (__bf16*)(ws + base + 5 * SZ + 524288);
  __bf16* po3 = (__bf16*)(ws + base + 5 * SZ + 524288 + SZ);
  // total ws use: ~30 MB

  (void)hipFuncSetAttribute((const void*)attn_k,
                            hipFuncAttributeMaxDynamicSharedMemorySize, 131072);

  gn_part_k<<<256, 256, 0, stream>>>(x, part);
  gn_fin_k<<<1, 256, 0, stream>>>(part, stats);
  conv_w_k<<<192, 256, 0, stream>>>(w_qkv, w_proj, wq_b, wp_b);
  gn_apply_k<<<256, 256, 0, stream>>>(x, gamma, beta, stats, xn);
  qkv_k<<<1536, 256, 0, stream>>>(xn, wq_b, b_qkv, qw, kw, vtw);
  attn_k<<<256, 512, 131072, stream>>>(qw, kw, vtw, hw, xn, po2, po3, ml);
  merge4_k<<<256, 256, 0, stream>>>(hw, xn, po2, po3, ml);
  proj_k<<<512, 256, 0, stream>>>(hw, wp_b, b_proj, x, out);
}

// Round 5
// 285.549 us; speedup vs baseline: 1.0008x; 1.0008x over previous
//
#include <hip/hip_runtime.h>

typedef __bf16 bf16x8 __attribute__((ext_vector_type(8)));
typedef float  f32x4  __attribute__((ext_vector_type(4)));
typedef float  f32x16 __attribute__((ext_vector_type(16)));
typedef float  f32x2  __attribute__((ext_vector_type(2)));
typedef unsigned int uint32;
typedef unsigned int u32x4 __attribute__((ext_vector_type(4)));
typedef unsigned int u32x2 __attribute__((ext_vector_type(2)));

#define MFMA16(a, b, c) __builtin_amdgcn_mfma_f32_16x16x32_bf16((a), (b), (c), 0, 0, 0)
#define MFMA32(a, b, c) __builtin_amdgcn_mfma_f32_32x32x16_bf16((a), (b), (c), 0, 0, 0)
// global -> LDS direct DMA, 16B per lane; dest = wave-uniform base + lane*16
#define GLL(gsrc, ldst) __builtin_amdgcn_global_load_lds( \
    (const __attribute__((address_space(1))) uint32*)(gsrc), \
    (__attribute__((address_space(3))) uint32*)(ldst), 16, 0, 0)

static constexpr int Cch = 128;   // channels
static constexpr int Nvox = 8192; // D*H*W = 8*32*32

__device__ inline unsigned int pkbf(float x, float y) {
  unsigned short ux = __builtin_bit_cast(unsigned short, (__bf16)x);
  unsigned short uy = __builtin_bit_cast(unsigned short, (__bf16)y);
  return (unsigned int)ux | ((unsigned int)uy << 16);
}
__device__ inline float bflo(unsigned int u) {
  return __builtin_bit_cast(float, u << 16);
}
__device__ inline float bfhi(unsigned int u) {
  return __builtin_bit_cast(float, u & 0xffff0000u);
}

// ---------------- K1a: GroupNorm partial sums: 256 blocks -------------------
__global__ __launch_bounds__(256) void gn_part_k(const float* __restrict__ x,
                                                 f32x2* __restrict__ part) {
  int bg = blockIdx.x >> 4, pt = blockIdx.x & 15;
  const f32x4* xb = (const f32x4*)(x + (size_t)bg * 131072 + (size_t)pt * 8192);
  float s = 0.f, ss = 0.f;
  for (int i = threadIdx.x; i < 2048; i += 256) {
    f32x4 v = xb[i];
    s += (v.x + v.y) + (v.z + v.w);
    ss += (v.x * v.x + v.y * v.y) + (v.z * v.z + v.w * v.w);
  }
#pragma unroll
  for (int off = 32; off; off >>= 1) {
    s  += __shfl_down(s, off);
    ss += __shfl_down(ss, off);
  }
  __shared__ float rb[4], rbss[4];
  if ((threadIdx.x & 63) == 0) { rb[threadIdx.x >> 6] = s; rbss[threadIdx.x >> 6] = ss; }
  __syncthreads();
  if (threadIdx.x == 0) {
    f32x2 o; o.x = rb[0] + rb[1] + rb[2] + rb[3];
    o.y = rbss[0] + rbss[1] + rbss[2] + rbss[3];
    part[blockIdx.x] = o;
  }
}

// ---------------- K1b: GroupNorm finish: 1 block ----------------------------
__global__ __launch_bounds__(256) void gn_fin_k(const f32x2* __restrict__ part,
                                                float* __restrict__ stats) {
  int tid = threadIdx.x;
  f32x2 v = part[tid];
  float s = v.x, ss = v.y;
#pragma unroll
  for (int off = 1; off < 16; off <<= 1) {
    s += __shfl_xor(s, off);
    ss += __shfl_xor(ss, off);
  }
  if ((tid & 15) == 0) {
    int bg = tid >> 4;
    const float invn = 1.f / 131072.f;
    float mean = s * invn;
    float var = ss * invn - mean * mean;
    stats[bg] = mean;
    stats[16 + bg] = rsqrtf(var + 1e-5f);
  }
}

// ---------------- K2: weight f32 -> bf16 ----------------
__global__ __launch_bounds__(256) void conv_w_k(const float* __restrict__ wq,
                                                const float* __restrict__ wp,
                                                __bf16* __restrict__ wqb,
                                                __bf16* __restrict__ wpb) {
  int i = blockIdx.x * 256 + threadIdx.x;
  if (i < 384 * 128) wqb[i] = (__bf16)wq[i];
  if (i < 128 * 128) wpb[i] = (__bf16)wp[i];
}

// ---------------- K3: normalize + transpose to xn[b][n][c] (bf16) ------------
__global__ __launch_bounds__(256) void gn_apply_k(const float* __restrict__ x,
                                                  const float* __restrict__ gamma,
                                                  const float* __restrict__ beta,
                                                  const float* __restrict__ stats,
                                                  __bf16* __restrict__ xn) {
  __shared__ __bf16 t[64][136];
  int b = blockIdx.x >> 7;
  int n0 = (blockIdx.x & 127) << 6;
  const float* xb = x + (size_t)b * Cch * Nvox;
  for (int i = threadIdx.x; i < 128 * 64; i += 256) {
    int c = i >> 6, nl = i & 63;
    int g = c >> 4;
    float mean = stats[b * 8 + g];
    float rstd = stats[16 + b * 8 + g];
    float v = xb[(size_t)c * Nvox + n0 + nl];
    t[nl][c] = (__bf16)((v - mean) * rstd * gamma[c] + beta[c]);
  }
  __syncthreads();
  __bf16* outb = xn + (size_t)b * Nvox * Cch;
  for (int i = threadIdx.x; i < 64 * 16; i += 256) {
    int row = i >> 4, ch = (i & 15) << 3;
    *reinterpret_cast<bf16x8*>(&outb[(size_t)(n0 + row) * Cch + ch]) =
        *reinterpret_cast<const bf16x8*>(&t[row][ch]);
  }
}

// ---------------- K4: QKV GEMM (MFMA bf16) -----------------------------------
__global__ __launch_bounds__(256) void qkv_k(const __bf16* __restrict__ xn,
                                             const __bf16* __restrict__ wq,
                                             const float* __restrict__ b_qkv,
                                             __bf16* __restrict__ q,
                                             __bf16* __restrict__ k,
                                             __bf16* __restrict__ vt) {
  int id = blockIdx.x;               // 2 * 6 * 128 blocks
  int b = id / 768;
  int rr = id % 768;
  int o0 = (rr >> 7) * 64;
  int n0 = (rr & 127) * 64;
  int w = threadIdx.x >> 6, l = threadIdx.x & 63;
  int lr = l & 15, lh = l >> 4;
  int ow = o0 + w * 16;

  bf16x8 a[4];
#pragma unroll
  for (int kc = 0; kc < 4; kc++)
    a[kc] = *reinterpret_cast<const bf16x8*>(&wq[(size_t)(ow + lr) * 128 + kc * 32 + lh * 8]);

  const __bf16* xb = xn + (size_t)b * Nvox * Cch;
#pragma unroll
  for (int ns = 0; ns < 4; ns++) {
    f32x4 acc = {0.f, 0.f, 0.f, 0.f};
#pragma unroll
    for (int kc = 0; kc < 4; kc++) {
      bf16x8 bf = *reinterpret_cast<const bf16x8*>(
          &xb[(size_t)(n0 + ns * 16 + lr) * Cch + kc * 32 + lh * 8]);
      acc = MFMA16(a[kc], bf, acc);
    }
#pragma unroll
    for (int r2 = 0; r2 < 4; r2++) {
      int o = ow + lh * 4 + r2;
      int n = n0 + ns * 16 + lr;
      float val = acc[r2] + b_qkv[o];
      if (o < 128)
        q[((size_t)b * Nvox + n) * Cch + o] = (__bf16)val;
      else if (o < 256)
        k[((size_t)b * Nvox + n) * Cch + (o - 128)] = (__bf16)val;
      else
        vt[((size_t)b * Cch + (o - 256)) * Nvox + n] = (__bf16)val;
    }
  }
}

// ---------------- K5: flash attention v4b ------------------------------------
// Identical structure to v4 (round 4) but with __launch_bounds__(512, 1):
// the (512,2) variant capped VGPRs at 128 and spilled all accumulators to
// scratch (285MB fetch + 204MB write of spill traffic per dispatch).
// 128KB dynamic LDS already limits to 1 block/CU, so (512,1) loses nothing.
__global__ __launch_bounds__(512, 1) void attn_k(const __bf16* __restrict__ q,
                                                 const __bf16* __restrict__ kk,
                                                 const __bf16* __restrict__ vt,
                                                 __bf16* __restrict__ po0,
                                                 __bf16* __restrict__ po1,
                                                 __bf16* __restrict__ po2,
                                                 __bf16* __restrict__ po3,
                                                 f32x2* __restrict__ ml) {
  extern __shared__ char smem[];   // 128KB: K[2][32K] | V[2][32K]
  const int bi = blockIdx.x;
  const int kq = bi & 3;
  const int b = (bi >> 2) & 1;
  const int qgrp = bi >> 3;            // 0..31
  const int w = threadIdx.x >> 6;      // 0..7
  const int l = threadIdx.x & 63;
  const int l31 = l & 31, h = l >> 5;
  const int g = w >> 2, wqt = w & 3;   // k-subhalf, q-tile
  const int sw = (l & 7) << 4;         // read-side XOR swizzle

  const char* kbase = (const char*)kk + ((size_t)b * 8192 + (size_t)kq * 2048) * 256;
  const char* vbase = (const char*)vt + (size_t)b * 2097152 + (size_t)kq * 4096;

  // Q B-fragments in registers: col q = l31, k-elems h*8..+8
  const __bf16* qptr = q + ((size_t)b * 8192 + (size_t)qgrp * 256 + (size_t)wqt * 64) * 128;
  bf16x8 qa[2][8];
#pragma unroll
  for (int sq = 0; sq < 2; sq++)
#pragma unroll
    for (int dc = 0; dc < 8; dc++)
      qa[sq][dc] = *reinterpret_cast<const bf16x8*>(
          &qptr[(size_t)(sq * 32 + l31) * 128 + dc * 16 + h * 8]);

  f32x16 O[4][2];
#pragma unroll
  for (int cb = 0; cb < 4; cb++)
#pragma unroll
    for (int sq = 0; sq < 2; sq++)
#pragma unroll
      for (int r = 0; r < 16; r++) O[cb][sq][r] = 0.f;
  float msc[2] = {-1e30f, -1e30f};
  float lsum[2] = {0.f, 0.f};

  const float k2 = 0.08838834764831845f * 1.4426950408889634f; // scale*log2e

  // stage one 128-row K/V tile: warps 0-3 K (8KB each), warps 4-7 V (8KB each)
  auto stage = [&](int t, int bs) {
    int c0 = (w & 3) * 8;
    if (w < 4) {
      const char* kt = kbase + (size_t)t * 32768;
      char* dst = smem + bs * 32768;
#pragma unroll
      for (int it = 0; it < 8; ++it) {
        int o = (c0 + it) * 1024 + l * 16;
        int row = o >> 8, col = (o & 255) ^ ((row & 7) << 4);
        GLL(kt + (size_t)row * 256 + col, dst + (c0 + it) * 1024);
      }
    } else {
      const char* vtt = vbase + (size_t)t * 256;
      char* dst = smem + 65536 + bs * 32768;
#pragma unroll
      for (int it = 0; it < 8; ++it) {
        int o = (c0 + it) * 1024 + l * 16;
        int row = o >> 8, col = (o & 255) ^ ((row & 7) << 4);
        GLL(vtt + (size_t)row * 16384 + col, dst + (c0 + it) * 1024);
      }
    }
  };

  stage(0, 0);
  int cur = 0;
  const int NT = 16;

  for (int t = 0; t < NT; ++t) {
    __syncthreads();                   // buf[cur] staged (vmcnt drained)
    if (t + 1 < NT) stage(t + 1, cur ^ 1);

    const char* Kb = smem + cur * 32768;
    const char* Vb = smem + 65536 + cur * 32768;

    // ---- QK^T (swapped): St[ks][sq], rows=k, cols=q -----------------------
    f32x16 St[2][2];
#pragma unroll
    for (int ks = 0; ks < 2; ks++)
#pragma unroll
      for (int sq = 0; sq < 2; sq++)
#pragma unroll
        for (int r = 0; r < 16; r++) St[ks][sq][r] = 0.f;
#pragma unroll
    for (int ks = 0; ks < 2; ks++) {
      int krow = g * 64 + ks * 32 + l31;
#pragma unroll
      for (int dc = 0; dc < 8; dc++) {
        bf16x8 kf = *reinterpret_cast<const bf16x8*>(
            Kb + (size_t)krow * 256 + ((dc * 32 + h * 16) ^ sw));
#pragma unroll
        for (int sq = 0; sq < 2; sq++)
          St[ks][sq] = MFMA32(kf, qa[sq][dc], St[ks][sq]);
      }
    }

    // ---- online softmax (per q = lane col) + in-register P packing --------
    u32x4 pk[2][2][2];  // [sq][ks][kc]
#pragma unroll
    for (int sq = 0; sq < 2; sq++) {
      // tree max over the 32 in-lane values
      f32x16 mm;
#pragma unroll
      for (int r = 0; r < 16; r++) mm[r] = fmaxf(St[0][sq][r], St[1][sq][r]);
#pragma unroll
      for (int st = 8; st; st >>= 1)
#pragma unroll
        for (int r = 0; r < 8; r++)
          if (r < st) mm[r] = fmaxf(mm[r], mm[r + st]);
      float pm = fmaxf(mm[0], __shfl_xor(mm[0], 32));
      float pms = pm * k2;
      if (__any(pms > msc[sq] + 8.f)) {   // defer-max (T13)
        float nm = fmaxf(msc[sq], pms);
        float al = __builtin_amdgcn_exp2f(msc[sq] - nm);
        msc[sq] = nm;
        lsum[sq] *= al;
#pragma unroll
        for (int cb = 0; cb < 4; cb++)
#pragma unroll
          for (int r = 0; r < 16; r++) O[cb][sq][r] *= al;
      }
      float p[2][16];
#pragma unroll
      for (int ks = 0; ks < 2; ks++)
#pragma unroll
        for (int r = 0; r < 16; r++)
          p[ks][r] = __builtin_amdgcn_exp2f(St[ks][sq][r] * k2 - msc[sq]);
      // tree sum
      f32x16 sm;
#pragma unroll
      for (int r = 0; r < 16; r++) sm[r] = p[0][r] + p[1][r];
#pragma unroll
      for (int st = 8; st; st >>= 1)
#pragma unroll
        for (int r = 0; r < 8; r++)
          if (r < st) sm[r] = sm[r] + sm[r + st];
      float rs = sm[0] + __shfl_xor(sm[0], 32);
      lsum[sq] += rs;
      // pack to PV B-frags
#pragma unroll
      for (int ks = 0; ks < 2; ks++) {
#pragma unroll
        for (int kc = 0; kc < 2; kc++) {
          int bs = kc * 8;
          unsigned int a0 = pkbf(p[ks][bs + 0], p[ks][bs + 1]);
          unsigned int a1 = pkbf(p[ks][bs + 2], p[ks][bs + 3]);
          unsigned int b0 = pkbf(p[ks][bs + 4], p[ks][bs + 5]);
          unsigned int b1 = pkbf(p[ks][bs + 6], p[ks][bs + 7]);
          unsigned int sa0 = __shfl_xor(a0, 32), sa1 = __shfl_xor(a1, 32);
          unsigned int sb0 = __shfl_xor(b0, 32), sb1 = __shfl_xor(b1, 32);
          bool lo = (l < 32);
          u32x4 pv;
          pv[0] = lo ? a0 : sb0;
          pv[1] = lo ? a1 : sb1;
          pv[2] = lo ? sa0 : b0;
          pv[3] = lo ? sa1 : b1;
          pk[sq][ks][kc] = pv;
        }
      }
    }

    // ---- PV: O^T[c][q] += V^T-frag x P-frag --------------------------------
#pragma unroll
    for (int ks = 0; ks < 2; ks++) {
#pragma unroll
      for (int kc = 0; kc < 2; kc++) {
#pragma unroll
        for (int cb = 0; cb < 4; cb++) {
          bf16x8 vf = *reinterpret_cast<const bf16x8*>(
              Vb + (size_t)(cb * 32 + l31) * 256 +
              ((g * 128 + ks * 64 + kc * 32 + h * 16) ^ sw));
#pragma unroll
          for (int sq = 0; sq < 2; sq++)
            O[cb][sq] = MFMA32(vf, __builtin_bit_cast(bf16x8, pk[sq][ks][kc]),
                               O[cb][sq]);
        }
      }
    }
    cur ^= 1;
  }

  // ---- in-block merge of the two k-subhalves (bf16 via LDS) ----------------
  __syncthreads();                    // tile bufs dead; reuse for merge
  char* mO = smem;                    // 16 chunks x 256 slots x 16B = 64KB
  float* mlb = (float*)(smem + 65536); // [4 wq][32 q][2 sq][2]
  if (g == 1) {
#pragma unroll
    for (int cb = 0; cb < 4; cb++)
#pragma unroll
      for (int sq = 0; sq < 2; sq++)
#pragma unroll
        for (int hf = 0; hf < 2; hf++) {
          int j = (cb * 2 + sq) * 2 + hf;
          u32x4 pv;
#pragma unroll
          for (int i = 0; i < 4; i++)
            pv[i] = pkbf(O[cb][sq][hf * 8 + 2 * i], O[cb][sq][hf * 8 + 2 * i + 1]);
          *reinterpret_cast<u32x4*>(mO + ((size_t)j * 256 + wqt * 64 + l) * 16) = pv;
        }
    if (l < 32) {
#pragma unroll
      for (int sq = 0; sq < 2; sq++) {
        mlb[((wqt * 32 + l31) * 2 + sq) * 2 + 0] = msc[sq];
        mlb[((wqt * 32 + l31) * 2 + sq) * 2 + 1] = lsum[sq];
      }
    }
  }
  __syncthreads();
  if (g == 0) {
    __bf16* po = (kq == 0) ? po0 : (kq == 1) ? po1 : (kq == 2) ? po2 : po3;
#pragma unroll
    for (int sq = 0; sq < 2; sq++) {
      float m2 = mlb[((wqt * 32 + l31) * 2 + sq) * 2 + 0];
      float l2 = mlb[((wqt * 32 + l31) * 2 + sq) * 2 + 1];
      float M = fmaxf(msc[sq], m2);
      float e1 = __builtin_amdgcn_exp2f(msc[sq] - M);
      float e2 = __builtin_amdgcn_exp2f(m2 - M);
      lsum[sq] = e1 * lsum[sq] + e2 * l2;
      msc[sq] = M;
#pragma unroll
      for (int cb = 0; cb < 4; cb++)
#pragma unroll
        for (int hf = 0; hf < 2; hf++) {
          int j = (cb * 2 + sq) * 2 + hf;
          u32x4 pv = *reinterpret_cast<const u32x4*>(
              mO + ((size_t)j * 256 + wqt * 64 + l) * 16);
#pragma unroll
          for (int i = 0; i < 4; i++) {
            O[cb][sq][hf * 8 + 2 * i] =
                e1 * O[cb][sq][hf * 8 + 2 * i] + e2 * bflo(pv[i]);
            O[cb][sq][hf * 8 + 2 * i + 1] =
                e1 * O[cb][sq][hf * 8 + 2 * i + 1] + e2 * bfhi(pv[i]);
          }
        }
      // write unnormalized partial O^T (bf16) + (m, l)
      int qg = b * 8192 + qgrp * 256 + wqt * 64 + sq * 32 + l31;
#pragma unroll
      for (int cb = 0; cb < 4; cb++) {
#pragma unroll
        for (int rq = 0; rq < 4; rq++) {
          int c = cb * 32 + rq * 8 + h * 4;
          u32x2 wv;
          wv[0] = pkbf(O[cb][sq][rq * 4 + 0], O[cb][sq][rq * 4 + 1]);
          wv[1] = pkbf(O[cb][sq][rq * 4 + 2], O[cb][sq][rq * 4 + 3]);
          *reinterpret_cast<u32x2*>((char*)po + ((size_t)qg * 128 + c) * 2) = wv;
        }
      }
      if (l < 32) {
        f32x2 v; v.x = msc[sq]; v.y = lsum[sq];
        ml[(size_t)kq * 16384 + qg] = v;
      }
    }
  }
}

// ---------------- K5b: merge the four k-quarters -----------------------------
__global__ __launch_bounds__(256) void merge4_k(__bf16* __restrict__ po0,
                                                const __bf16* __restrict__ po1,
                                                const __bf16* __restrict__ po2,
                                                const __bf16* __restrict__ po3,
                                                const f32x2* __restrict__ ml) {
  int t = blockIdx.x * 256 + threadIdx.x;   // 65536 threads
  int qg = t >> 2;
  int c0 = (t & 3) * 32;
  f32x2 a0 = ml[qg], a1 = ml[16384 + qg], a2 = ml[32768 + qg], a3 = ml[49152 + qg];
  float M = fmaxf(fmaxf(a0.x, a1.x), fmaxf(a2.x, a3.x));
  float e0 = __builtin_amdgcn_exp2f(a0.x - M);
  float e1 = __builtin_amdgcn_exp2f(a1.x - M);
  float e2 = __builtin_amdgcn_exp2f(a2.x - M);
  float e3 = __builtin_amdgcn_exp2f(a3.x - M);
  float L = e0 * a0.y + e1 * a1.y + e2 * a2.y + e3 * a3.y;
  float invL = 1.f / L;
  float c0f = e0 * invL, c1f = e1 * invL, c2f = e2 * invL, c3f = e3 * invL;
#pragma unroll
  for (int j = 0; j < 4; j++) {
    size_t off = (size_t)qg * 128 + c0 + j * 8;
    bf16x8 v0 = *reinterpret_cast<const bf16x8*>(&po0[off]);
    bf16x8 v1 = *reinterpret_cast<const bf16x8*>(&po1[off]);
    bf16x8 v2 = *reinterpret_cast<const bf16x8*>(&po2[off]);
    bf16x8 v3 = *reinterpret_cast<const bf16x8*>(&po3[off]);
    bf16x8 o;
#pragma unroll
    for (int i = 0; i < 8; i++)
      o[i] = (__bf16)(c0f * (float)v0[i] + c1f * (float)v1[i] +
                      c2f * (float)v2[i] + c3f * (float)v3[i]);
    *reinterpret_cast<bf16x8*>(&po0[off]) = o;
  }
}

// ---------------- K6: proj GEMM + bias + residual ----------------------------
__global__ __launch_bounds__(256) void proj_k(const __bf16* __restrict__ h,
                                              const __bf16* __restrict__ wp,
                                              const float* __restrict__ b_proj,
                                              const float* __restrict__ x,
                                              float* __restrict__ out) {
  int id = blockIdx.x;            // 2 * 2 * 128
  int b = id >> 8;
  int co0 = ((id >> 7) & 1) * 64;
  int n0 = (id & 127) * 64;
  int w = threadIdx.x >> 6, l = threadIdx.x & 63;
  int lr = l & 15, lh = l >> 4;
  int cow = co0 + w * 16;

  bf16x8 a[4];
#pragma unroll
  for (int kc = 0; kc < 4; kc++)
    a[kc] = *reinterpret_cast<const bf16x8*>(&wp[(size_t)(cow + lr) * 128 + kc * 32 + lh * 8]);

  const __bf16* hb = h + (size_t)b * Nvox * Cch;
#pragma unroll
  for (int ns = 0; ns < 4; ns++) {
    f32x4 acc = {0.f, 0.f, 0.f, 0.f};
#pragma unroll
    for (int kc = 0; kc < 4; kc++) {
      bf16x8 bf = *reinterpret_cast<const bf16x8*>(
          &hb[(size_t)(n0 + ns * 16 + lr) * Cch + kc * 32 + lh * 8]);
      acc = MFMA16(a[kc], bf, acc);
    }
#pragma unroll
    for (int r2 = 0; r2 < 4; r2++) {
      int co = cow + lh * 4 + r2;
      int n = n0 + ns * 16 + lr;
      size_t idx = ((size_t)b * Cch + co) * Nvox + n;
      out[idx] = x[idx] + b_proj[co] + acc[r2];
    }
  }
}

extern "C" void kernel_launch(void* const* d_in, const int* in_sizes, int n_in,
                              void* d_out, int out_size, void* d_ws, size_t ws_size,
                              hipStream_t stream) {
  const float* x      = (const float*)d_in[0];
  const float* gamma  = (const float*)d_in[1];
  const float* beta   = (const float*)d_in[2];
  const float* w_qkv  = (const float*)d_in[3];
  const float* b_qkv  = (const float*)d_in[4];
  const float* w_proj = (const float*)d_in[5];
  const float* b_proj = (const float*)d_in[6];
  float* out = (float*)d_out;

  char* ws = (char*)d_ws;
  float*  stats = (float*)ws;                      // 128 B
  f32x2*  part  = (f32x2*)(ws + 256);              // 2 KB
  __bf16* wq_b  = (__bf16*)(ws + 4096);            // 98304 B
  __bf16* wp_b  = (__bf16*)(ws + 4096 + 98304);    // 32768 B
  size_t base = 135168;
  const size_t SZ = (size_t)2 * Nvox * Cch * sizeof(__bf16); // 4 MiB
  __bf16* xn  = (__bf16*)(ws + base + 0 * SZ);     // reused as po1
  __bf16* qw  = (__bf16*)(ws + base + 1 * SZ);
  __bf16* kw  = (__bf16*)(ws + base + 2 * SZ);
  __bf16* vtw = (__bf16*)(ws + base + 3 * SZ);
  __bf16* hw  = (__bf16*)(ws + base + 4 * SZ);     // po0, then merged h
  f32x2*  ml  = (f32x2*)(ws + base + 5 * SZ);      // 512 KB
  __bf16* po2 = (__bf16*)(ws + base + 5 * SZ + 524288);
  __bf16* po3 = (__bf16*)(ws + base + 5 * SZ + 524288 + SZ);
  // total ws use: ~30 MB

  (void)hipFuncSetAttribute((const void*)attn_k,
                            hipFuncAttributeMaxDynamicSharedMemorySize, 131072);

  gn_part_k<<<256, 256, 0, stream>>>(x, part);
  gn_fin_k<<<1, 256, 0, stream>>>(part, stats);
  conv_w_k<<<192, 256, 0, stream>>>(w_qkv, w_proj, wq_b, wp_b);
  gn_apply_k<<<256, 256, 0, stream>>>(x, gamma, beta, stats, xn);
  qkv_k<<<1536, 256, 0, stream>>>(xn, wq_b, b_qkv, qw, kw, vtw);
  attn_k<<<256, 512, 131072, stream>>>(qw, kw, vtw, hw, xn, po2, po3, ml);
  merge4_k<<<256, 256, 0, stream>>>(hw, xn, po2, po3, ml);
  proj_k<<<512, 256, 0, stream>>>(hw, wp_b, b_proj, x, out);
}

// Round 7
// 194.919 us; speedup vs baseline: 1.4661x; 1.4650x over previous
//
#include <hip/hip_runtime.h>

typedef __bf16 bf16x8 __attribute__((ext_vector_type(8)));
typedef float  f32x4  __attribute__((ext_vector_type(4)));
typedef float  f32x16 __attribute__((ext_vector_type(16)));
typedef float  f32x2  __attribute__((ext_vector_type(2)));
typedef unsigned int uint32;
typedef unsigned int u32x4 __attribute__((ext_vector_type(4)));
typedef unsigned int u32x2 __attribute__((ext_vector_type(2)));

#define MFMA16(a, b, c) __builtin_amdgcn_mfma_f32_16x16x32_bf16((a), (b), (c), 0, 0, 0)
#define MFMA32(a, b, c) __builtin_amdgcn_mfma_f32_32x32x16_bf16((a), (b), (c), 0, 0, 0)
// global -> LDS direct DMA, 16B per lane; dest = wave-uniform base + lane*16
#define GLL(gsrc, ldst) __builtin_amdgcn_global_load_lds( \
    (const __attribute__((address_space(1))) uint32*)(gsrc), \
    (__attribute__((address_space(3))) uint32*)(ldst), 16, 0, 0)

static constexpr int Cch = 128;   // channels
static constexpr int Nvox = 8192; // D*H*W = 8*32*32

__device__ inline unsigned int pkbf(float x, float y) {
  unsigned short ux = __builtin_bit_cast(unsigned short, (__bf16)x);
  unsigned short uy = __builtin_bit_cast(unsigned short, (__bf16)y);
  return (unsigned int)ux | ((unsigned int)uy << 16);
}

// ---------------- K1a: GroupNorm partial sums: 256 blocks -------------------
__global__ __launch_bounds__(256) void gn_part_k(const float* __restrict__ x,
                                                 f32x2* __restrict__ part) {
  int bg = blockIdx.x >> 4, pt = blockIdx.x & 15;
  const f32x4* xb = (const f32x4*)(x + (size_t)bg * 131072 + (size_t)pt * 8192);
  float s = 0.f, ss = 0.f;
  for (int i = threadIdx.x; i < 2048; i += 256) {
    f32x4 v = xb[i];
    s += (v.x + v.y) + (v.z + v.w);
    ss += (v.x * v.x + v.y * v.y) + (v.z * v.z + v.w * v.w);
  }
#pragma unroll
  for (int off = 32; off; off >>= 1) {
    s  += __shfl_down(s, off);
    ss += __shfl_down(ss, off);
  }
  __shared__ float rb[4], rbss[4];
  if ((threadIdx.x & 63) == 0) { rb[threadIdx.x >> 6] = s; rbss[threadIdx.x >> 6] = ss; }
  __syncthreads();
  if (threadIdx.x == 0) {
    f32x2 o; o.x = rb[0] + rb[1] + rb[2] + rb[3];
    o.y = rbss[0] + rbss[1] + rbss[2] + rbss[3];
    part[blockIdx.x] = o;
  }
}

// ---------------- K1b: GroupNorm finish: 1 block ----------------------------
__global__ __launch_bounds__(256) void gn_fin_k(const f32x2* __restrict__ part,
                                                float* __restrict__ stats) {
  int tid = threadIdx.x;
  f32x2 v = part[tid];
  float s = v.x, ss = v.y;
#pragma unroll
  for (int off = 1; off < 16; off <<= 1) {
    s += __shfl_xor(s, off);
    ss += __shfl_xor(ss, off);
  }
  if ((tid & 15) == 0) {
    int bg = tid >> 4;
    const float invn = 1.f / 131072.f;
    float mean = s * invn;
    float var = ss * invn - mean * mean;
    stats[bg] = mean;
    stats[16 + bg] = rsqrtf(var + 1e-5f);
  }
}

// ---------------- K2: weight f32 -> bf16 ----------------
__global__ __launch_bounds__(256) void conv_w_k(const float* __restrict__ wq,
                                                const float* __restrict__ wp,
                                                __bf16* __restrict__ wqb,
                                                __bf16* __restrict__ wpb) {
  int i = blockIdx.x * 256 + threadIdx.x;
  if (i < 384 * 128) wqb[i] = (__bf16)wq[i];
  if (i < 128 * 128) wpb[i] = (__bf16)wp[i];
}

// ---------------- K3: normalize + transpose to xn[b][n][c] (bf16) ------------
__global__ __launch_bounds__(256) void gn_apply_k(const float* __restrict__ x,
                                                  const float* __restrict__ gamma,
                                                  const float* __restrict__ beta,
                                                  const float* __restrict__ stats,
                                                  __bf16* __restrict__ xn) {
  __shared__ __bf16 t[64][136];
  int b = blockIdx.x >> 7;
  int n0 = (blockIdx.x & 127) << 6;
  const float* xb = x + (size_t)b * Cch * Nvox;
  for (int i = threadIdx.x; i < 128 * 64; i += 256) {
    int c = i >> 6, nl = i & 63;
    int g = c >> 4;
    float mean = stats[b * 8 + g];
    float rstd = stats[16 + b * 8 + g];
    float v = xb[(size_t)c * Nvox + n0 + nl];
    t[nl][c] = (__bf16)((v - mean) * rstd * gamma[c] + beta[c]);
  }
  __syncthreads();
  __bf16* outb = xn + (size_t)b * Nvox * Cch;
  for (int i = threadIdx.x; i < 64 * 16; i += 256) {
    int row = i >> 4, ch = (i & 15) << 3;
    *reinterpret_cast<bf16x8*>(&outb[(size_t)(n0 + row) * Cch + ch]) =
        *reinterpret_cast<const bf16x8*>(&t[row][ch]);
  }
}

// ---------------- K4: QKV GEMM (MFMA bf16) -----------------------------------
__global__ __launch_bounds__(256) void qkv_k(const __bf16* __restrict__ xn,
                                             const __bf16* __restrict__ wq,
                                             const float* __restrict__ b_qkv,
                                             __bf16* __restrict__ q,
                                             __bf16* __restrict__ k,
                                             __bf16* __restrict__ vt) {
  int id = blockIdx.x;               // 2 * 6 * 128 blocks
  int b = id / 768;
  int rr = id % 768;
  int o0 = (rr >> 7) * 64;
  int n0 = (rr & 127) * 64;
  int w = threadIdx.x >> 6, l = threadIdx.x & 63;
  int lr = l & 15, lh = l >> 4;
  int ow = o0 + w * 16;

  bf16x8 a[4];
#pragma unroll
  for (int kc = 0; kc < 4; kc++)
    a[kc] = *reinterpret_cast<const bf16x8*>(&wq[(size_t)(ow + lr) * 128 + kc * 32 + lh * 8]);

  const __bf16* xb = xn + (size_t)b * Nvox * Cch;
#pragma unroll
  for (int ns = 0; ns < 4; ns++) {
    f32x4 acc = {0.f, 0.f, 0.f, 0.f};
#pragma unroll
    for (int kc = 0; kc < 4; kc++) {
      bf16x8 bf = *reinterpret_cast<const bf16x8*>(
          &xb[(size_t)(n0 + ns * 16 + lr) * Cch + kc * 32 + lh * 8]);
      acc = MFMA16(a[kc], bf, acc);
    }
#pragma unroll
    for (int r2 = 0; r2 < 4; r2++) {
      int o = ow + lh * 4 + r2;
      int n = n0 + ns * 16 + lr;
      float val = acc[r2] + b_qkv[o];
      if (o < 128)
        q[((size_t)b * Nvox + n) * Cch + o] = (__bf16)val;
      else if (o < 256)
        k[((size_t)b * Nvox + n) * Cch + (o - 128)] = (__bf16)val;
      else
        vt[((size_t)b * Cch + (o - 256)) * Nvox + n] = (__bf16)val;
    }
  }
}

// ---------------- K5: flash attention v6b ------------------------------------
// Same geometry as v6 (round 6): 256 blocks = qgrp(32) x b(2) x kq(4),
// 256 threads = 4 warps = 1 wave/SIMD (512-reg budget, no spill).
// FIX vs v6: explicit `s_waitcnt vmcnt(0) lgkmcnt(0)` + sched_barrier(0)
// immediately before each __syncthreads(). v6 relied on the compiler tying
// global_load_lds's LDS-write effect to the barrier drain; if that waitcnt
// is omitted, a wave passes the barrier with its DMA in flight and other
// waves read a half-staged tile -> the replay-only divergence seen in r6.
__global__ __launch_bounds__(256, 1) void attn_k(const __bf16* __restrict__ q,
                                                 const __bf16* __restrict__ kk,
                                                 const __bf16* __restrict__ vt,
                                                 __bf16* __restrict__ po0,
                                                 __bf16* __restrict__ po1,
                                                 __bf16* __restrict__ po2,
                                                 __bf16* __restrict__ po3,
                                                 f32x2* __restrict__ ml) {
  extern __shared__ char smem[];   // 128KB: buf0 [K 32K | V 32K], buf1 same
  const int bi = blockIdx.x;
  const int kq = bi & 3;
  const int b = (bi >> 2) & 1;
  const int qgrp = bi >> 3;            // 0..31
  const int w = threadIdx.x >> 6;      // 0..3 = q-tile
  const int l = threadIdx.x & 63;
  const int l31 = l & 31, h = l >> 5;
  const int swl = (l31 & 15) << 4;     // read-side XOR swizzle (row = l31-based)

  const char* kbase = (const char*)kk + ((size_t)b * 8192 + (size_t)kq * 2048) * 256;
  const char* vbase = (const char*)vt + (size_t)b * 2097152 + (size_t)kq * 4096;

  // Q B-fragments in registers: col q = l31, k-elems h*8..+8
  const __bf16* qptr = q + ((size_t)b * 8192 + (size_t)qgrp * 256 + (size_t)w * 64) * 128;
  bf16x8 qa[2][8];
#pragma unroll
  for (int sq = 0; sq < 2; sq++)
#pragma unroll
    for (int dc = 0; dc < 8; dc++)
      qa[sq][dc] = *reinterpret_cast<const bf16x8*>(
          &qptr[(size_t)(sq * 32 + l31) * 128 + dc * 16 + h * 8]);

  f32x16 O[4][2];
#pragma unroll
  for (int cb = 0; cb < 4; cb++)
#pragma unroll
    for (int sq = 0; sq < 2; sq++)
#pragma unroll
      for (int r = 0; r < 16; r++) O[cb][sq][r] = 0.f;
  float msc[2] = {-1e30f, -1e30f};
  float lsum[2] = {0.f, 0.f};

  const float k2 = 0.08838834764831845f * 1.4426950408889634f; // scale*log2e

  // stage one 128-row K/V tile pair (64KB): warps 0-1 K, warps 2-3 V; 16KB ea.
  auto stage = [&](int t, int bs) {
    const int half = w & 1;
    if (w < 2) {
      const char* src = kbase + (size_t)t * 32768 + (size_t)half * 16384;
      char* dst = smem + bs * 65536 + half * 16384;
#pragma unroll
      for (int it = 0; it < 16; ++it) {
        int o = it * 1024 + l * 16;
        int row = o >> 8, col = (o & 255) ^ ((row & 15) << 4);
        GLL(src + (size_t)row * 256 + col, dst + it * 1024);
      }
    } else {
      const char* src = vbase + (size_t)t * 256 + (size_t)half * 64 * 16384;
      char* dst = smem + bs * 65536 + 32768 + half * 16384;
#pragma unroll
      for (int it = 0; it < 16; ++it) {
        int o = it * 1024 + l * 16;
        int row = o >> 8, col = (o & 255) ^ ((row & 15) << 4);
        GLL(src + (size_t)row * 16384 + col, dst + it * 1024);
      }
    }
  };

  stage(0, 0);
  int cur = 0;
  const int NT = 16;

  for (int t = 0; t < NT; ++t) {
    // explicit drain: this wave's DMA (and LDS ops) complete before barrier
    asm volatile("s_waitcnt vmcnt(0) lgkmcnt(0)" ::: "memory");
    __builtin_amdgcn_sched_barrier(0);
    __syncthreads();                   // buf[cur] staged for ALL waves
    if (t + 1 < NT) stage(t + 1, cur ^ 1);

    const char* Kb = smem + cur * 65536;
    const char* Vb = Kb + 32768;

#pragma unroll
    for (int ss = 0; ss < 2; ++ss) {   // two 64-k sub-steps, regs reused
      // ---- QK^T (swapped): St[ks][sq], rows=k, cols=q ---------------------
      f32x16 St[2][2];
#pragma unroll
      for (int ks = 0; ks < 2; ks++)
#pragma unroll
        for (int sq = 0; sq < 2; sq++)
#pragma unroll
          for (int r = 0; r < 16; r++) St[ks][sq][r] = 0.f;
#pragma unroll
      for (int ks = 0; ks < 2; ks++) {
        int krow = ss * 64 + ks * 32 + l31;   // (krow&15)==(l31&15)
#pragma unroll
        for (int dc = 0; dc < 8; dc++) {
          bf16x8 kf = *reinterpret_cast<const bf16x8*>(
              Kb + (size_t)krow * 256 + ((dc * 32 + h * 16) ^ swl));
#pragma unroll
          for (int sq = 0; sq < 2; sq++)
            St[ks][sq] = MFMA32(kf, qa[sq][dc], St[ks][sq]);
        }
      }

      // ---- online softmax (per q = lane col) + in-register P packing ------
      u32x4 pk[2][2][2];  // [sq][ks][kc]
#pragma unroll
      for (int sq = 0; sq < 2; sq++) {
        // tree max over the 32 in-lane values
        f32x16 mm;
#pragma unroll
        for (int r = 0; r < 16; r++) mm[r] = fmaxf(St[0][sq][r], St[1][sq][r]);
#pragma unroll
        for (int st = 8; st; st >>= 1)
#pragma unroll
          for (int r = 0; r < 8; r++)
            if (r < st) mm[r] = fmaxf(mm[r], mm[r + st]);
        float pm = fmaxf(mm[0], __shfl_xor(mm[0], 32));
        float pms = pm * k2;
        if (__any(pms > msc[sq] + 8.f)) {   // defer-max (T13)
          float nm = fmaxf(msc[sq], pms);
          float al = __builtin_amdgcn_exp2f(msc[sq] - nm);
          msc[sq] = nm;
          lsum[sq] *= al;
#pragma unroll
          for (int cb = 0; cb < 4; cb++)
#pragma unroll
            for (int r = 0; r < 16; r++) O[cb][sq][r] *= al;
        }
        float p[2][16];
#pragma unroll
        for (int ks = 0; ks < 2; ks++)
#pragma unroll
          for (int r = 0; r < 16; r++)
            p[ks][r] = __builtin_amdgcn_exp2f(St[ks][sq][r] * k2 - msc[sq]);
        // tree sum
        f32x16 sm;
#pragma unroll
        for (int r = 0; r < 16; r++) sm[r] = p[0][r] + p[1][r];
#pragma unroll
        for (int st = 8; st; st >>= 1)
#pragma unroll
          for (int r = 0; r < 8; r++)
            if (r < st) sm[r] = sm[r] + sm[r + st];
        lsum[sq] += sm[0] + __shfl_xor(sm[0], 32);
        // pack to PV B-frags
#pragma unroll
        for (int ks = 0; ks < 2; ks++) {
#pragma unroll
          for (int kc = 0; kc < 2; kc++) {
            int bs = kc * 8;
            unsigned int a0 = pkbf(p[ks][bs + 0], p[ks][bs + 1]);
            unsigned int a1 = pkbf(p[ks][bs + 2], p[ks][bs + 3]);
            unsigned int b0 = pkbf(p[ks][bs + 4], p[ks][bs + 5]);
            unsigned int b1 = pkbf(p[ks][bs + 6], p[ks][bs + 7]);
            unsigned int sa0 = __shfl_xor(a0, 32), sa1 = __shfl_xor(a1, 32);
            unsigned int sb0 = __shfl_xor(b0, 32), sb1 = __shfl_xor(b1, 32);
            bool lo = (l < 32);
            u32x4 pv;
            pv[0] = lo ? a0 : sb0;
            pv[1] = lo ? a1 : sb1;
            pv[2] = lo ? sa0 : b0;
            pv[3] = lo ? sa1 : b1;
            pk[sq][ks][kc] = pv;
          }
        }
      }

      // ---- PV: O^T[c][q] += V^T-frag x P-frag ------------------------------
#pragma unroll
      for (int ks = 0; ks < 2; ks++) {
#pragma unroll
        for (int kc = 0; kc < 2; kc++) {
#pragma unroll
          for (int cb = 0; cb < 4; cb++) {
            bf16x8 vf = *reinterpret_cast<const bf16x8*>(
                Vb + (size_t)(cb * 32 + l31) * 256 +
                ((ss * 128 + ks * 64 + kc * 32 + h * 16) ^ swl));
#pragma unroll
            for (int sq = 0; sq < 2; sq++)
              O[cb][sq] = MFMA32(vf, __builtin_bit_cast(bf16x8, pk[sq][ks][kc]),
                                 O[cb][sq]);
          }
        }
      }
    }
    cur ^= 1;
  }

  // ---- epilogue: write unnormalized partial O^T (bf16) + (m, l) ------------
  __bf16* po = (kq == 0) ? po0 : (kq == 1) ? po1 : (kq == 2) ? po2 : po3;
#pragma unroll
  for (int sq = 0; sq < 2; sq++) {
    int qg = b * 8192 + qgrp * 256 + w * 64 + sq * 32 + l31;
#pragma unroll
    for (int cb = 0; cb < 4; cb++) {
#pragma unroll
      for (int rq = 0; rq < 4; rq++) {
        int c = cb * 32 + rq * 8 + h * 4;
        u32x2 wv;
        wv[0] = pkbf(O[cb][sq][rq * 4 + 0], O[cb][sq][rq * 4 + 1]);
        wv[1] = pkbf(O[cb][sq][rq * 4 + 2], O[cb][sq][rq * 4 + 3]);
        *reinterpret_cast<u32x2*>((char*)po + ((size_t)qg * 128 + c) * 2) = wv;
      }
    }
    if (l < 32) {
      f32x2 v; v.x = msc[sq]; v.y = lsum[sq];
      ml[(size_t)kq * 16384 + qg] = v;
    }
  }
}

// ---------------- K5b: merge the four k-quarters -----------------------------
__global__ __launch_bounds__(256) void merge4_k(__bf16* __restrict__ po0,
                                                const __bf16* __restrict__ po1,
                                                const __bf16* __restrict__ po2,
                                                const __bf16* __restrict__ po3,
                                                const f32x2* __restrict__ ml) {
  int t = blockIdx.x * 256 + threadIdx.x;   // 65536 threads
  int qg = t >> 2;
  int c0 = (t & 3) * 32;
  f32x2 a0 = ml[qg], a1 = ml[16384 + qg], a2 = ml[32768 + qg], a3 = ml[49152 + qg];
  float M = fmaxf(fmaxf(a0.x, a1.x), fmaxf(a2.x, a3.x));
  float e0 = __builtin_amdgcn_exp2f(a0.x - M);
  float e1 = __builtin_amdgcn_exp2f(a1.x - M);
  float e2 = __builtin_amdgcn_exp2f(a2.x - M);
  float e3 = __builtin_amdgcn_exp2f(a3.x - M);
  float L = e0 * a0.y + e1 * a1.y + e2 * a2.y + e3 * a3.y;
  float invL = 1.f / L;
  float c0f = e0 * invL, c1f = e1 * invL, c2f = e2 * invL, c3f = e3 * invL;
#pragma unroll
  for (int j = 0; j < 4; j++) {
    size_t off = (size_t)qg * 128 + c0 + j * 8;
    bf16x8 v0 = *reinterpret_cast<const bf16x8*>(&po0[off]);
    bf16x8 v1 = *reinterpret_cast<const bf16x8*>(&po1[off]);
    bf16x8 v2 = *reinterpret_cast<const bf16x8*>(&po2[off]);
    bf16x8 v3 = *reinterpret_cast<const bf16x8*>(&po3[off]);
    bf16x8 o;
#pragma unroll
    for (int i = 0; i < 8; i++)
      o[i] = (__bf16)(c0f * (float)v0[i] + c1f * (float)v1[i] +
                      c2f * (float)v2[i] + c3f * (float)v3[i]);
    *reinterpret_cast<bf16x8*>(&po0[off]) = o;
  }
}

// ---------------- K6: proj GEMM + bias + residual ----------------------------
__global__ __launch_bounds__(256) void proj_k(const __bf16* __restrict__ h,
                                              const __bf16* __restrict__ wp,
                                              const float* __restrict__ b_proj,
                                              const float* __restrict__ x,
                                              float* __restrict__ out) {
  int id = blockIdx.x;            // 2 * 2 * 128
  int b = id >> 8;
  int co0 = ((id >> 7) & 1) * 64;
  int n0 = (id & 127) * 64;
  int w = threadIdx.x >> 6, l = threadIdx.x & 63;
  int lr = l & 15, lh = l >> 4;
  int cow = co0 + w * 16;

  bf16x8 a[4];
#pragma unroll
  for (int kc = 0; kc < 4; kc++)
    a[kc] = *reinterpret_cast<const bf16x8*>(&wp[(size_t)(cow + lr) * 128 + kc * 32 + lh * 8]);

  const __bf16* hb = h + (size_t)b * Nvox * Cch;
#pragma unroll
  for (int ns = 0; ns < 4; ns++) {
    f32x4 acc = {0.f, 0.f, 0.f, 0.f};
#pragma unroll
    for (int kc = 0; kc < 4; kc++) {
      bf16x8 bf = *reinterpret_cast<const bf16x8*>(
          &hb[(size_t)(n0 + ns * 16 + lr) * Cch + kc * 32 + lh * 8]);
      acc = MFMA16(a[kc], bf, acc);
    }
#pragma unroll
    for (int r2 = 0; r2 < 4; r2++) {
      int co = cow + lh * 4 + r2;
      int n = n0 + ns * 16 + lr;
      size_t idx = ((size_t)b * Cch + co) * Nvox + n;
      out[idx] = x[idx] + b_proj[co] + acc[r2];
    }
  }
}

extern "C" void kernel_launch(void* const* d_in, const int* in_sizes, int n_in,
                              void* d_out, int out_size, void* d_ws, size_t ws_size,
                              hipStream_t stream) {
  const float* x      = (const float*)d_in[0];
  const float* gamma  = (const float*)d_in[1];
  const float* beta   = (const float*)d_in[2];
  const float* w_qkv  = (const float*)d_in[3];
  const float* b_qkv  = (const float*)d_in[4];
  const float* w_proj = (const float*)d_in[5];
  const float* b_proj = (const float*)d_in[6];
  float* out = (float*)d_out;

  char* ws = (char*)d_ws;
  float*  stats = (float*)ws;                      // 128 B
  f32x2*  part  = (f32x2*)(ws + 256);              // 2 KB
  __bf16* wq_b  = (__bf16*)(ws + 4096);            // 98304 B
  __bf16* wp_b  = (__bf16*)(ws + 4096 + 98304);    // 32768 B
  size_t base = 135168;
  const size_t SZ = (size_t)2 * Nvox * Cch * sizeof(__bf16); // 4 MiB
  __bf16* xn  = (__bf16*)(ws + base + 0 * SZ);     // reused as po1
  __bf16* qw  = (__bf16*)(ws + base + 1 * SZ);
  __bf16* kw  = (__bf16*)(ws + base + 2 * SZ);
  __bf16* vtw = (__bf16*)(ws + base + 3 * SZ);
  __bf16* hw  = (__bf16*)(ws + base + 4 * SZ);     // po0, then merged h
  f32x2*  ml  = (f32x2*)(ws + base + 5 * SZ);      // 512 KB
  __bf16* po2 = (__bf16*)(ws + base + 5 * SZ + 524288);
  __bf16* po3 = (__bf16*)(ws + base + 5 * SZ + 524288 + SZ);
  // total ws use: ~30 MB

  (void)hipFuncSetAttribute((const void*)attn_k,
                            hipFuncAttributeMaxDynamicSharedMemorySize, 131072);

  gn_part_k<<<256, 256, 0, stream>>>(x, part);
  gn_fin_k<<<1, 256, 0, stream>>>(part, stats);
  conv_w_k<<<192, 256, 0, stream>>>(w_qkv, w_proj, wq_b, wp_b);
  gn_apply_k<<<256, 256, 0, stream>>>(x, gamma, beta, stats, xn);
  qkv_k<<<1536, 256, 0, stream>>>(xn, wq_b, b_qkv, qw, kw, vtw);
  attn_k<<<256, 256, 131072, stream>>>(qw, kw, vtw, hw, xn, po2, po3, ml);
  merge4_k<<<256, 256, 0, stream>>>(hw, xn, po2, po3, ml);
  proj_k<<<512, 256, 0, stream>>>(hw, wp_b, b_proj, x, out);
}

// Round 8
// 141.962 us; speedup vs baseline: 2.0130x; 1.3730x over previous
//
#include <hip/hip_runtime.h>

typedef __bf16 bf16x8 __attribute__((ext_vector_type(8)));
typedef float  f32x4  __attribute__((ext_vector_type(4)));
typedef float  f32x16 __attribute__((ext_vector_type(16)));
typedef float  f32x2  __attribute__((ext_vector_type(2)));
typedef unsigned int uint32;
typedef unsigned int u32x4 __attribute__((ext_vector_type(4)));
typedef unsigned int u32x2 __attribute__((ext_vector_type(2)));

#define MFMA16(a, b, c) __builtin_amdgcn_mfma_f32_16x16x32_bf16((a), (b), (c), 0, 0, 0)
#define MFMA32(a, b, c) __builtin_amdgcn_mfma_f32_32x32x16_bf16((a), (b), (c), 0, 0, 0)
// global -> LDS direct DMA, 16B per lane; dest = wave-uniform base + lane*16
#define GLL(gsrc, ldst) __builtin_amdgcn_global_load_lds( \
    (const __attribute__((address_space(1))) uint32*)(gsrc), \
    (__attribute__((address_space(3))) uint32*)(ldst), 16, 0, 0)

static constexpr int Cch = 128;   // channels
static constexpr int Nvox = 8192; // D*H*W = 8*32*32

__device__ inline unsigned int pkbf(float x, float y) {
  unsigned short ux = __builtin_bit_cast(unsigned short, (__bf16)x);
  unsigned short uy = __builtin_bit_cast(unsigned short, (__bf16)y);
  return (unsigned int)ux | ((unsigned int)uy << 16);
}

// ---------------- K1a: GroupNorm partial sums: 256 blocks -------------------
__global__ __launch_bounds__(256) void gn_part_k(const float* __restrict__ x,
                                                 f32x2* __restrict__ part) {
  int bg = blockIdx.x >> 4, pt = blockIdx.x & 15;
  const f32x4* xb = (const f32x4*)(x + (size_t)bg * 131072 + (size_t)pt * 8192);
  float s = 0.f, ss = 0.f;
  for (int i = threadIdx.x; i < 2048; i += 256) {
    f32x4 v = xb[i];
    s += (v.x + v.y) + (v.z + v.w);
    ss += (v.x * v.x + v.y * v.y) + (v.z * v.z + v.w * v.w);
  }
#pragma unroll
  for (int off = 32; off; off >>= 1) {
    s  += __shfl_down(s, off);
    ss += __shfl_down(ss, off);
  }
  __shared__ float rb[4], rbss[4];
  if ((threadIdx.x & 63) == 0) { rb[threadIdx.x >> 6] = s; rbss[threadIdx.x >> 6] = ss; }
  __syncthreads();
  if (threadIdx.x == 0) {
    f32x2 o; o.x = rb[0] + rb[1] + rb[2] + rb[3];
    o.y = rbss[0] + rbss[1] + rbss[2] + rbss[3];
    part[blockIdx.x] = o;
  }
}

// ---------------- K1b: GroupNorm finish: 1 block ----------------------------
__global__ __launch_bounds__(256) void gn_fin_k(const f32x2* __restrict__ part,
                                                float* __restrict__ stats) {
  int tid = threadIdx.x;
  f32x2 v = part[tid];
  float s = v.x, ss = v.y;
#pragma unroll
  for (int off = 1; off < 16; off <<= 1) {
    s += __shfl_xor(s, off);
    ss += __shfl_xor(ss, off);
  }
  if ((tid & 15) == 0) {
    int bg = tid >> 4;
    const float invn = 1.f / 131072.f;
    float mean = s * invn;
    float var = ss * invn - mean * mean;
    stats[bg] = mean;
    stats[16 + bg] = rsqrtf(var + 1e-5f);
  }
}

// ---------------- K2: weight f32 -> bf16 ----------------
__global__ __launch_bounds__(256) void conv_w_k(const float* __restrict__ wq,
                                                const float* __restrict__ wp,
                                                __bf16* __restrict__ wqb,
                                                __bf16* __restrict__ wpb) {
  int i = blockIdx.x * 256 + threadIdx.x;
  if (i < 384 * 128) wqb[i] = (__bf16)wq[i];
  if (i < 128 * 128) wpb[i] = (__bf16)wp[i];
}

// ---------------- K3: normalize + transpose to xn[b][n][c] (bf16) ------------
__global__ __launch_bounds__(256) void gn_apply_k(const float* __restrict__ x,
                                                  const float* __restrict__ gamma,
                                                  const float* __restrict__ beta,
                                                  const float* __restrict__ stats,
                                                  __bf16* __restrict__ xn) {
  __shared__ __bf16 t[64][136];
  int b = blockIdx.x >> 7;
  int n0 = (blockIdx.x & 127) << 6;
  const float* xb = x + (size_t)b * Cch * Nvox;
  for (int i = threadIdx.x; i < 128 * 64; i += 256) {
    int c = i >> 6, nl = i & 63;
    int g = c >> 4;
    float mean = stats[b * 8 + g];
    float rstd = stats[16 + b * 8 + g];
    float v = xb[(size_t)c * Nvox + n0 + nl];
    t[nl][c] = (__bf16)((v - mean) * rstd * gamma[c] + beta[c]);
  }
  __syncthreads();
  __bf16* outb = xn + (size_t)b * Nvox * Cch;
  for (int i = threadIdx.x; i < 64 * 16; i += 256) {
    int row = i >> 4, ch = (i & 15) << 3;
    *reinterpret_cast<bf16x8*>(&outb[(size_t)(n0 + row) * Cch + ch]) =
        *reinterpret_cast<const bf16x8*>(&t[row][ch]);
  }
}

// ---------------- K4: QKV GEMM (MFMA bf16) -----------------------------------
__global__ __launch_bounds__(256) void qkv_k(const __bf16* __restrict__ xn,
                                             const __bf16* __restrict__ wq,
                                             const float* __restrict__ b_qkv,
                                             __bf16* __restrict__ q,
                                             __bf16* __restrict__ k,
                                             __bf16* __restrict__ vt) {
  int id = blockIdx.x;               // 2 * 6 * 128 blocks
  int b = id / 768;
  int rr = id % 768;
  int o0 = (rr >> 7) * 64;
  int n0 = (rr & 127) * 64;
  int w = threadIdx.x >> 6, l = threadIdx.x & 63;
  int lr = l & 15, lh = l >> 4;
  int ow = o0 + w * 16;

  bf16x8 a[4];
#pragma unroll
  for (int kc = 0; kc < 4; kc++)
    a[kc] = *reinterpret_cast<const bf16x8*>(&wq[(size_t)(ow + lr) * 128 + kc * 32 + lh * 8]);

  const __bf16* xb = xn + (size_t)b * Nvox * Cch;
#pragma unroll
  for (int ns = 0; ns < 4; ns++) {
    f32x4 acc = {0.f, 0.f, 0.f, 0.f};
#pragma unroll
    for (int kc = 0; kc < 4; kc++) {
      bf16x8 bf = *reinterpret_cast<const bf16x8*>(
          &xb[(size_t)(n0 + ns * 16 + lr) * Cch + kc * 32 + lh * 8]);
      acc = MFMA16(a[kc], bf, acc);
    }
#pragma unroll
    for (int r2 = 0; r2 < 4; r2++) {
      int o = ow + lh * 4 + r2;
      int n = n0 + ns * 16 + lr;
      float val = acc[r2] + b_qkv[o];
      if (o < 128)
        q[((size_t)b * Nvox + n) * Cch + o] = (__bf16)val;
      else if (o < 256)
        k[((size_t)b * Nvox + n) * Cch + (o - 128)] = (__bf16)val;
      else
        vt[((size_t)b * Cch + (o - 256)) * Nvox + n] = (__bf16)val;
    }
  }
}

// ---------------- K5: flash attention v7 -------------------------------------
// 512 blocks = qgrp(64) x b(2) x kq(4); bi%8 = b*4+kq -> XCD-affine KV slices.
// 256 threads = 4 warps, q=32 per warp (QBLK=128). KVBLK=64 double-buffered:
// LDS = 2 x (K 16KB + V 16KB) = 64KB -> 2 blocks/CU = 2 waves/SIMD (TLP hides
// the latency that 1 wave/SIMD exposed in v6b: busy-sum was only 48%).
// __launch_bounds__(256,2) caps VGPR at 256 (need ~180).
// Each block: k-quarter (2048 rows) in 32 iters. 4 kq partials merged by
// merge4_k. Race guard (explicit vmcnt drain before barrier) retained.
__global__ __launch_bounds__(256, 2) void attn_k(const __bf16* __restrict__ q,
                                                 const __bf16* __restrict__ kk,
                                                 const __bf16* __restrict__ vt,
                                                 __bf16* __restrict__ po0,
                                                 __bf16* __restrict__ po1,
                                                 __bf16* __restrict__ po2,
                                                 __bf16* __restrict__ po3,
                                                 f32x2* __restrict__ ml) {
  extern __shared__ char smem[];   // 64KB: buf{0,1} x [K 16K | V 16K]
  const int bi = blockIdx.x;
  const int kq = bi & 3;
  const int b = (bi >> 2) & 1;
  const int qgrp = bi >> 3;            // 0..63
  const int w = threadIdx.x >> 6;      // 0..3 = q-tile (32 q each)
  const int l = threadIdx.x & 63;
  const int l31 = l & 31, h = l >> 5;
  const int swl16 = (l31 & 15) << 4;   // K-read swizzle (256B rows)
  const int swl8  = (l31 & 7) << 4;    // V-read swizzle (128B rows)

  const char* kbase = (const char*)kk + ((size_t)b * 8192 + (size_t)kq * 2048) * 256;
  const char* vbase = (const char*)vt + (size_t)b * 2097152 + (size_t)kq * 4096;

  // Q B-fragments in registers: col q = l31, k-elems h*8..+8
  const __bf16* qptr = q + ((size_t)b * 8192 + (size_t)qgrp * 128 + (size_t)w * 32) * 128;
  bf16x8 qa[8];
#pragma unroll
  for (int dc = 0; dc < 8; dc++)
    qa[dc] = *reinterpret_cast<const bf16x8*>(
        &qptr[(size_t)l31 * 128 + dc * 16 + h * 8]);

  f32x16 O[4];
#pragma unroll
  for (int cb = 0; cb < 4; cb++)
#pragma unroll
    for (int r = 0; r < 16; r++) O[cb][r] = 0.f;
  float msc = -1e30f;
  float lsum = 0.f;

  const float k2 = 0.08838834764831845f * 1.4426950408889634f; // scale*log2e

  // stage one 64-row K/V tile pair (32KB): warps 0-1 K, warps 2-3 V; 8KB each.
  auto stage = [&](int t, int bs) {
    if (w < 2) {
      const char* src = kbase + (size_t)t * 16384;   // K rows 256B
      char* dst = smem + bs * 32768;
#pragma unroll
      for (int it = 0; it < 8; ++it) {
        int ob = (w * 8 + it) * 1024;
        int o = ob + l * 16;
        int row = o >> 8, col = (o & 255) ^ ((row & 15) << 4);
        GLL(src + (size_t)row * 256 + col, dst + ob);
      }
    } else {
      const char* src = vbase + (size_t)t * 128;     // V^T c-rows 16384B
      char* dst = smem + bs * 32768 + 16384;
#pragma unroll
      for (int it = 0; it < 8; ++it) {
        int ob = ((w - 2) * 8 + it) * 1024;
        int o = ob + l * 16;
        int row = o >> 7, col = (o & 127) ^ ((row & 7) << 4);
        GLL(src + (size_t)row * 16384 + col, dst + ob);
      }
    }
  };

  stage(0, 0);
  int cur = 0;
  const int NT = 32;

  for (int t = 0; t < NT; ++t) {
    // explicit drain: this wave's DMA completes before the barrier
    asm volatile("s_waitcnt vmcnt(0) lgkmcnt(0)" ::: "memory");
    __builtin_amdgcn_sched_barrier(0);
    __syncthreads();                   // buf[cur] staged for ALL waves
    if (t + 1 < NT) stage(t + 1, cur ^ 1);

    const char* Kb = smem + cur * 32768;
    const char* Vb = Kb + 16384;

    // ---- QK^T (swapped): St[ks], rows=k (ks*32+l31), cols=q (l31) ---------
    f32x16 St[2];
#pragma unroll
    for (int ks = 0; ks < 2; ks++)
#pragma unroll
      for (int r = 0; r < 16; r++) St[ks][r] = 0.f;
#pragma unroll
    for (int ks = 0; ks < 2; ks++) {
      int krow = ks * 32 + l31;        // (krow&15)==(l31&15)
#pragma unroll
      for (int dc = 0; dc < 8; dc++) {
        bf16x8 kf = *reinterpret_cast<const bf16x8*>(
            Kb + (size_t)krow * 256 + ((dc * 32 + h * 16) ^ swl16));
        St[ks] = MFMA32(kf, qa[dc], St[ks]);
      }
    }

    // ---- online softmax (per q = lane col) + in-register P packing --------
    // tree max over the 32 in-lane values
    f32x16 mm;
#pragma unroll
    for (int r = 0; r < 16; r++) mm[r] = fmaxf(St[0][r], St[1][r]);
#pragma unroll
    for (int st = 8; st; st >>= 1)
#pragma unroll
      for (int r = 0; r < 8; r++)
        if (r < st) mm[r] = fmaxf(mm[r], mm[r + st]);
    float pm = fmaxf(mm[0], __shfl_xor(mm[0], 32));
    float pms = pm * k2;
    if (__any(pms > msc + 8.f)) {      // defer-max (T13)
      float nm = fmaxf(msc, pms);
      float al = __builtin_amdgcn_exp2f(msc - nm);
      msc = nm;
      lsum *= al;
#pragma unroll
      for (int cb = 0; cb < 4; cb++)
#pragma unroll
        for (int r = 0; r < 16; r++) O[cb][r] *= al;
    }
    float p[2][16];
#pragma unroll
    for (int ks = 0; ks < 2; ks++)
#pragma unroll
      for (int r = 0; r < 16; r++)
        p[ks][r] = __builtin_amdgcn_exp2f(St[ks][r] * k2 - msc);
    // tree sum
    f32x16 sm;
#pragma unroll
    for (int r = 0; r < 16; r++) sm[r] = p[0][r] + p[1][r];
#pragma unroll
    for (int st = 8; st; st >>= 1)
#pragma unroll
      for (int r = 0; r < 8; r++)
        if (r < st) sm[r] = sm[r] + sm[r + st];
    lsum += sm[0] + __shfl_xor(sm[0], 32);
    // pack to PV B-frags
    u32x4 pk[2][2];  // [ks][kc]
#pragma unroll
    for (int ks = 0; ks < 2; ks++) {
#pragma unroll
      for (int kc = 0; kc < 2; kc++) {
        int bs = kc * 8;
        unsigned int a0 = pkbf(p[ks][bs + 0], p[ks][bs + 1]);
        unsigned int a1 = pkbf(p[ks][bs + 2], p[ks][bs + 3]);
        unsigned int b0 = pkbf(p[ks][bs + 4], p[ks][bs + 5]);
        unsigned int b1 = pkbf(p[ks][bs + 6], p[ks][bs + 7]);
        unsigned int sa0 = __shfl_xor(a0, 32), sa1 = __shfl_xor(a1, 32);
        unsigned int sb0 = __shfl_xor(b0, 32), sb1 = __shfl_xor(b1, 32);
        bool lo = (l < 32);
        u32x4 pv;
        pv[0] = lo ? a0 : sb0;
        pv[1] = lo ? a1 : sb1;
        pv[2] = lo ? sa0 : b0;
        pv[3] = lo ? sa1 : b1;
        pk[ks][kc] = pv;
      }
    }

    // ---- PV: O^T[c][q] += V^T-frag x P-frag --------------------------------
#pragma unroll
    for (int ks = 0; ks < 2; ks++) {
#pragma unroll
      for (int kc = 0; kc < 2; kc++) {
#pragma unroll
        for (int cb = 0; cb < 4; cb++) {
          bf16x8 vf = *reinterpret_cast<const bf16x8*>(
              Vb + (size_t)(cb * 32 + l31) * 128 +
              ((ks * 64 + kc * 32 + h * 16) ^ swl8));
          O[cb] = MFMA32(vf, __builtin_bit_cast(bf16x8, pk[ks][kc]), O[cb]);
        }
      }
    }
    cur ^= 1;
  }

  // ---- epilogue: write unnormalized partial O^T (bf16) + (m, l) ------------
  __bf16* po = (kq == 0) ? po0 : (kq == 1) ? po1 : (kq == 2) ? po2 : po3;
  int qg = b * 8192 + qgrp * 128 + w * 32 + l31;
#pragma unroll
  for (int cb = 0; cb < 4; cb++) {
#pragma unroll
    for (int rq = 0; rq < 4; rq++) {
      int c = cb * 32 + rq * 8 + h * 4;
      u32x2 wv;
      wv[0] = pkbf(O[cb][rq * 4 + 0], O[cb][rq * 4 + 1]);
      wv[1] = pkbf(O[cb][rq * 4 + 2], O[cb][rq * 4 + 3]);
      *reinterpret_cast<u32x2*>((char*)po + ((size_t)qg * 128 + c) * 2) = wv;
    }
  }
  if (l < 32) {
    f32x2 v; v.x = msc; v.y = lsum;
    ml[(size_t)kq * 16384 + qg] = v;
  }
}

// ---------------- K5b: merge the four k-quarters -----------------------------
__global__ __launch_bounds__(256) void merge4_k(__bf16* __restrict__ po0,
                                                const __bf16* __restrict__ po1,
                                                const __bf16* __restrict__ po2,
                                                const __bf16* __restrict__ po3,
                                                const f32x2* __restrict__ ml) {
  int t = blockIdx.x * 256 + threadIdx.x;   // 65536 threads
  int qg = t >> 2;
  int c0 = (t & 3) * 32;
  f32x2 a0 = ml[qg], a1 = ml[16384 + qg], a2 = ml[32768 + qg], a3 = ml[49152 + qg];
  float M = fmaxf(fmaxf(a0.x, a1.x), fmaxf(a2.x, a3.x));
  float e0 = __builtin_amdgcn_exp2f(a0.x - M);
  float e1 = __builtin_amdgcn_exp2f(a1.x - M);
  float e2 = __builtin_amdgcn_exp2f(a2.x - M);
  float e3 = __builtin_amdgcn_exp2f(a3.x - M);
  float L = e0 * a0.y + e1 * a1.y + e2 * a2.y + e3 * a3.y;
  float invL = 1.f / L;
  float c0f = e0 * invL, c1f = e1 * invL, c2f = e2 * invL, c3f = e3 * invL;
#pragma unroll
  for (int j = 0; j < 4; j++) {
    size_t off = (size_t)qg * 128 + c0 + j * 8;
    bf16x8 v0 = *reinterpret_cast<const bf16x8*>(&po0[off]);
    bf16x8 v1 = *reinterpret_cast<const bf16x8*>(&po1[off]);
    bf16x8 v2 = *reinterpret_cast<const bf16x8*>(&po2[off]);
    bf16x8 v3 = *reinterpret_cast<const bf16x8*>(&po3[off]);
    bf16x8 o;
#pragma unroll
    for (int i = 0; i < 8; i++)
      o[i] = (__bf16)(c0f * (float)v0[i] + c1f * (float)v1[i] +
                      c2f * (float)v2[i] + c3f * (float)v3[i]);
    *reinterpret_cast<bf16x8*>(&po0[off]) = o;
  }
}

// ---------------- K6: proj GEMM + bias + residual ----------------------------
__global__ __launch_bounds__(256) void proj_k(const __bf16* __restrict__ h,
                                              const __bf16* __restrict__ wp,
                                              const float* __restrict__ b_proj,
                                              const float* __restrict__ x,
                                              float* __restrict__ out) {
  int id = blockIdx.x;            // 2 * 2 * 128
  int b = id >> 8;
  int co0 = ((id >> 7) & 1) * 64;
  int n0 = (id & 127) * 64;
  int w = threadIdx.x >> 6, l = threadIdx.x & 63;
  int lr = l & 15, lh = l >> 4;
  int cow = co0 + w * 16;

  bf16x8 a[4];
#pragma unroll
  for (int kc = 0; kc < 4; kc++)
    a[kc] = *reinterpret_cast<const bf16x8*>(&wp[(size_t)(cow + lr) * 128 + kc * 32 + lh * 8]);

  const __bf16* hb = h + (size_t)b * Nvox * Cch;
#pragma unroll
  for (int ns = 0; ns < 4; ns++) {
    f32x4 acc = {0.f, 0.f, 0.f, 0.f};
#pragma unroll
    for (int kc = 0; kc < 4; kc++) {
      bf16x8 bf = *reinterpret_cast<const bf16x8*>(
          &hb[(size_t)(n0 + ns * 16 + lr) * Cch + kc * 32 + lh * 8]);
      acc = MFMA16(a[kc], bf, acc);
    }
#pragma unroll
    for (int r2 = 0; r2 < 4; r2++) {
      int co = cow + lh * 4 + r2;
      int n = n0 + ns * 16 + lr;
      size_t idx = ((size_t)b * Cch + co) * Nvox + n;
      out[idx] = x[idx] + b_proj[co] + acc[r2];
    }
  }
}

extern "C" void kernel_launch(void* const* d_in, const int* in_sizes, int n_in,
                              void* d_out, int out_size, void* d_ws, size_t ws_size,
                              hipStream_t stream) {
  const float* x      = (const float*)d_in[0];
  const float* gamma  = (const float*)d_in[1];
  const float* beta   = (const float*)d_in[2];
  const float* w_qkv  = (const float*)d_in[3];
  const float* b_qkv  = (const float*)d_in[4];
  const float* w_proj = (const float*)d_in[5];
  const float* b_proj = (const float*)d_in[6];
  float* out = (float*)d_out;

  char* ws = (char*)d_ws;
  float*  stats = (float*)ws;                      // 128 B
  f32x2*  part  = (f32x2*)(ws + 256);              // 2 KB
  __bf16* wq_b  = (__bf16*)(ws + 4096);            // 98304 B
  __bf16* wp_b  = (__bf16*)(ws + 4096 + 98304);    // 32768 B
  size_t base = 135168;
  const size_t SZ = (size_t)2 * Nvox * Cch * sizeof(__bf16); // 4 MiB
  __bf16* xn  = (__bf16*)(ws + base + 0 * SZ);     // reused as po1
  __bf16* qw  = (__bf16*)(ws + base + 1 * SZ);
  __bf16* kw  = (__bf16*)(ws + base + 2 * SZ);
  __bf16* vtw = (__bf16*)(ws + base + 3 * SZ);
  __bf16* hw  = (__bf16*)(ws + base + 4 * SZ);     // po0, then merged h
  f32x2*  ml  = (f32x2*)(ws + base + 5 * SZ);      // 512 KB
  __bf16* po2 = (__bf16*)(ws + base + 5 * SZ + 524288);
  __bf16* po3 = (__bf16*)(ws + base + 5 * SZ + 524288 + SZ);
  // total ws use: ~30 MB

  (void)hipFuncSetAttribute((const void*)attn_k,
                            hipFuncAttributeMaxDynamicSharedMemorySize, 65536);

  gn_part_k<<<256, 256, 0, stream>>>(x, part);
  gn_fin_k<<<1, 256, 0, stream>>>(part, stats);
  conv_w_k<<<192, 256, 0, stream>>>(w_qkv, w_proj, wq_b, wp_b);
  gn_apply_k<<<256, 256, 0, stream>>>(x, gamma, beta, stats, xn);
  qkv_k<<<1536, 256, 0, stream>>>(xn, wq_b, b_qkv, qw, kw, vtw);
  attn_k<<<512, 256, 65536, stream>>>(qw, kw, vtw, hw, xn, po2, po3, ml);
  merge4_k<<<256, 256, 0, stream>>>(hw, xn, po2, po3, ml);
  proj_k<<<512, 256, 0, stream>>>(hw, wp_b, b_proj, x, out);
}

// Round 9
// 133.876 us; speedup vs baseline: 2.1346x; 1.0604x over previous
//
#include <hip/hip_runtime.h>

typedef __bf16 bf16x8 __attribute__((ext_vector_type(8)));
typedef float  f32x4  __attribute__((ext_vector_type(4)));
typedef float  f32x16 __attribute__((ext_vector_type(16)));
typedef float  f32x2  __attribute__((ext_vector_type(2)));
typedef unsigned int uint32;
typedef unsigned int u32x4 __attribute__((ext_vector_type(4)));
typedef unsigned int u32x2 __attribute__((ext_vector_type(2)));

#define MFMA16(a, b, c) __builtin_amdgcn_mfma_f32_16x16x32_bf16((a), (b), (c), 0, 0, 0)
#define MFMA32(a, b, c) __builtin_amdgcn_mfma_f32_32x32x16_bf16((a), (b), (c), 0, 0, 0)
// global -> LDS direct DMA, 16B per lane; dest = wave-uniform base + lane*16
#define GLL(gsrc, ldst) __builtin_amdgcn_global_load_lds( \
    (const __attribute__((address_space(1))) uint32*)(gsrc), \
    (__attribute__((address_space(3))) uint32*)(ldst), 16, 0, 0)

static constexpr int Cch = 128;   // channels
static constexpr int Nvox = 8192; // D*H*W = 8*32*32

__device__ inline unsigned int pkbf(float x, float y) {
  unsigned short ux = __builtin_bit_cast(unsigned short, (__bf16)x);
  unsigned short uy = __builtin_bit_cast(unsigned short, (__bf16)y);
  return (unsigned int)ux | ((unsigned int)uy << 16);
}

// exchange halves: x' = {x[0:31], y[0:31]}, y' = {x[32:63], y[32:63]}
__device__ inline void lane32_swap(unsigned int& x, unsigned int& y) {
#if __has_builtin(__builtin_amdgcn_permlane32_swap)
  auto r = __builtin_amdgcn_permlane32_swap(x, y, false, false);
  x = r[0]; y = r[1];
#else
  unsigned int sx = (unsigned int)__shfl_xor((int)x, 32);
  unsigned int sy = (unsigned int)__shfl_xor((int)y, 32);
  bool lo = ((threadIdx.x & 63) < 32);
  unsigned int nx = lo ? x : sy;
  unsigned int ny = lo ? sx : y;
  x = nx; y = ny;
#endif
}
__device__ inline float red32_max(float v) {
  unsigned int a = __builtin_bit_cast(unsigned int, v), b = a;
  lane32_swap(a, b);
  return fmaxf(__builtin_bit_cast(float, a), __builtin_bit_cast(float, b));
}
__device__ inline float red32_sum(float v) {
  unsigned int a = __builtin_bit_cast(unsigned int, v), b = a;
  lane32_swap(a, b);
  return __builtin_bit_cast(float, a) + __builtin_bit_cast(float, b);
}

// ---------------- K1a: GroupNorm partial sums: 256 blocks -------------------
__global__ __launch_bounds__(256) void gn_part_k(const float* __restrict__ x,
                                                 f32x2* __restrict__ part) {
  int bg = blockIdx.x >> 4, pt = blockIdx.x & 15;
  const f32x4* xb = (const f32x4*)(x + (size_t)bg * 131072 + (size_t)pt * 8192);
  float s = 0.f, ss = 0.f;
  for (int i = threadIdx.x; i < 2048; i += 256) {
    f32x4 v = xb[i];
    s += (v.x + v.y) + (v.z + v.w);
    ss += (v.x * v.x + v.y * v.y) + (v.z * v.z + v.w * v.w);
  }
#pragma unroll
  for (int off = 32; off; off >>= 1) {
    s  += __shfl_down(s, off);
    ss += __shfl_down(ss, off);
  }
  __shared__ float rb[4], rbss[4];
  if ((threadIdx.x & 63) == 0) { rb[threadIdx.x >> 6] = s; rbss[threadIdx.x >> 6] = ss; }
  __syncthreads();
  if (threadIdx.x == 0) {
    f32x2 o; o.x = rb[0] + rb[1] + rb[2] + rb[3];
    o.y = rbss[0] + rbss[1] + rbss[2] + rbss[3];
    part[blockIdx.x] = o;
  }
}

// ---------------- K1b: GroupNorm finish: 1 block ----------------------------
__global__ __launch_bounds__(256) void gn_fin_k(const f32x2* __restrict__ part,
                                                float* __restrict__ stats) {
  int tid = threadIdx.x;
  f32x2 v = part[tid];
  float s = v.x, ss = v.y;
#pragma unroll
  for (int off = 1; off < 16; off <<= 1) {
    s += __shfl_xor(s, off);
    ss += __shfl_xor(ss, off);
  }
  if ((tid & 15) == 0) {
    int bg = tid >> 4;
    const float invn = 1.f / 131072.f;
    float mean = s * invn;
    float var = ss * invn - mean * mean;
    stats[bg] = mean;
    stats[16 + bg] = rsqrtf(var + 1e-5f);
  }
}

// ---------------- K2: weight f32 -> bf16 ----------------
__global__ __launch_bounds__(256) void conv_w_k(const float* __restrict__ wq,
                                                const float* __restrict__ wp,
                                                __bf16* __restrict__ wqb,
                                                __bf16* __restrict__ wpb) {
  int i = blockIdx.x * 256 + threadIdx.x;
  if (i < 384 * 128) wqb[i] = (__bf16)wq[i];
  if (i < 128 * 128) wpb[i] = (__bf16)wp[i];
}

// ---------------- K3: normalize + transpose to xn[b][n][c] (bf16) ------------
__global__ __launch_bounds__(256) void gn_apply_k(const float* __restrict__ x,
                                                  const float* __restrict__ gamma,
                                                  const float* __restrict__ beta,
                                                  const float* __restrict__ stats,
                                                  __bf16* __restrict__ xn) {
  __shared__ __bf16 t[64][136];
  int b = blockIdx.x >> 7;
  int n0 = (blockIdx.x & 127) << 6;
  const float* xb = x + (size_t)b * Cch * Nvox;
  for (int i = threadIdx.x; i < 128 * 64; i += 256) {
    int c = i >> 6, nl = i & 63;
    int g = c >> 4;
    float mean = stats[b * 8 + g];
    float rstd = stats[16 + b * 8 + g];
    float v = xb[(size_t)c * Nvox + n0 + nl];
    t[nl][c] = (__bf16)((v - mean) * rstd * gamma[c] + beta[c]);
  }
  __syncthreads();
  __bf16* outb = xn + (size_t)b * Nvox * Cch;
  for (int i = threadIdx.x; i < 64 * 16; i += 256) {
    int row = i >> 4, ch = (i & 15) << 3;
    *reinterpret_cast<bf16x8*>(&outb[(size_t)(n0 + row) * Cch + ch]) =
        *reinterpret_cast<const bf16x8*>(&t[row][ch]);
  }
}

// ---------------- K4: QKV GEMM (MFMA bf16) -----------------------------------
__global__ __launch_bounds__(256) void qkv_k(const __bf16* __restrict__ xn,
                                             const __bf16* __restrict__ wq,
                                             const float* __restrict__ b_qkv,
                                             __bf16* __restrict__ q,
                                             __bf16* __restrict__ k,
                                             __bf16* __restrict__ vt) {
  int id = blockIdx.x;               // 2 * 6 * 128 blocks
  int b = id / 768;
  int rr = id % 768;
  int o0 = (rr >> 7) * 64;
  int n0 = (rr & 127) * 64;
  int w = threadIdx.x >> 6, l = threadIdx.x & 63;
  int lr = l & 15, lh = l >> 4;
  int ow = o0 + w * 16;

  bf16x8 a[4];
#pragma unroll
  for (int kc = 0; kc < 4; kc++)
    a[kc] = *reinterpret_cast<const bf16x8*>(&wq[(size_t)(ow + lr) * 128 + kc * 32 + lh * 8]);

  const __bf16* xb = xn + (size_t)b * Nvox * Cch;
#pragma unroll
  for (int ns = 0; ns < 4; ns++) {
    f32x4 acc = {0.f, 0.f, 0.f, 0.f};
#pragma unroll
    for (int kc = 0; kc < 4; kc++) {
      bf16x8 bf = *reinterpret_cast<const bf16x8*>(
          &xb[(size_t)(n0 + ns * 16 + lr) * Cch + kc * 32 + lh * 8]);
      acc = MFMA16(a[kc], bf, acc);
    }
#pragma unroll
    for (int r2 = 0; r2 < 4; r2++) {
      int o = ow + lh * 4 + r2;
      int n = n0 + ns * 16 + lr;
      float val = acc[r2] + b_qkv[o];
      if (o < 128)
        q[((size_t)b * Nvox + n) * Cch + o] = (__bf16)val;
      else if (o < 256)
        k[((size_t)b * Nvox + n) * Cch + (o - 128)] = (__bf16)val;
      else
        vt[((size_t)b * Cch + (o - 256)) * Nvox + n] = (__bf16)val;
    }
  }
}

// ---------------- K5: flash attention v8 -------------------------------------
// Geometry as v7 (2 blocks/CU, 4 warps, q=32/warp, KVBLK=64 dbuf, kq=4).
// Changes vs v7 (both attack the LDS pipe, the measured binding resource):
//  1. permlane32_swap replaces all xor-32 shuffles (softmax max/sum + P-pack):
//     18 ds_bpermute/iter -> 10 VALU ops; frees ~11us of DS-pipe time.
//  2. V LDS tile re-laid as [64 rows][256B] (c and c+64 share a row, XOR
//     involution over bits 4-7 applied to GLL source AND reads): 16 swizzle
//     slots -> 2-way conflicts (free) instead of the 4-way inherent to
//     128B rows (4.2e6 conflict-cycles in r8).
__global__ __launch_bounds__(256, 2) void attn_k(const __bf16* __restrict__ q,
                                                 const __bf16* __restrict__ kk,
                                                 const __bf16* __restrict__ vt,
                                                 __bf16* __restrict__ po0,
                                                 __bf16* __restrict__ po1,
                                                 __bf16* __restrict__ po2,
                                                 __bf16* __restrict__ po3,
                                                 f32x2* __restrict__ ml) {
  extern __shared__ char smem[];   // 64KB: buf{0,1} x [K 16K | V 16K]
  const int bi = blockIdx.x;
  const int kq = bi & 3;
  const int b = (bi >> 2) & 1;
  const int qgrp = bi >> 3;            // 0..63
  const int w = threadIdx.x >> 6;      // 0..3 = q-tile (32 q each)
  const int l = threadIdx.x & 63;
  const int l31 = l & 31, h = l >> 5;
  const int swl16 = (l31 & 15) << 4;   // read swizzle for 256B rows (K and V)

  const char* kbase = (const char*)kk + ((size_t)b * 8192 + (size_t)kq * 2048) * 256;
  const char* vbase = (const char*)vt + (size_t)b * 2097152 + (size_t)kq * 4096;

  // Q B-fragments in registers: col q = l31, k-elems h*8..+8
  const __bf16* qptr = q + ((size_t)b * 8192 + (size_t)qgrp * 128 + (size_t)w * 32) * 128;
  bf16x8 qa[8];
#pragma unroll
  for (int dc = 0; dc < 8; dc++)
    qa[dc] = *reinterpret_cast<const bf16x8*>(
        &qptr[(size_t)l31 * 128 + dc * 16 + h * 8]);

  f32x16 O[4];
#pragma unroll
  for (int cb = 0; cb < 4; cb++)
#pragma unroll
    for (int r = 0; r < 16; r++) O[cb][r] = 0.f;
  float msc = -1e30f;
  float lsum = 0.f;

  const float k2 = 0.08838834764831845f * 1.4426950408889634f; // scale*log2e

  // stage one 64-row K/V tile pair (32KB): warps 0-1 K, warps 2-3 V; 8KB each.
  auto stage = [&](int t, int bs) {
    if (w < 2) {
      const char* src = kbase + (size_t)t * 16384;   // K rows 256B
      char* dst = smem + bs * 32768;
#pragma unroll
      for (int it = 0; it < 8; ++it) {
        int ob = (w * 8 + it) * 1024;
        int o = ob + l * 16;
        int row = o >> 8, col = (o & 255) ^ ((row & 15) << 4);
        GLL(src + (size_t)row * 256 + col, dst + ob);
      }
    } else {
      // V: LDS row r (256B) = { V^T[c=r][64k] , V^T[c=r+64][64k] }, swizzled
      const char* src = vbase + (size_t)t * 128;     // V^T c-rows 16384B
      char* dst = smem + bs * 32768 + 16384;
#pragma unroll
      for (int it = 0; it < 8; ++it) {
        int ob = ((w - 2) * 8 + it) * 1024;
        int o = ob + l * 16;
        int row = o >> 8;                            // 0..63
        int lcol = (o & 255) ^ ((row & 15) << 4);    // logical col (involution)
        int c = row + ((lcol >> 7) << 6);            // c = row or row+64
        GLL(src + (size_t)c * 16384 + (lcol & 127), dst + ob);
      }
    }
  };

  stage(0, 0);
  int cur = 0;
  const int NT = 32;

  for (int t = 0; t < NT; ++t) {
    // explicit drain: this wave's DMA completes before the barrier
    asm volatile("s_waitcnt vmcnt(0) lgkmcnt(0)" ::: "memory");
    __builtin_amdgcn_sched_barrier(0);
    __syncthreads();                   // buf[cur] staged for ALL waves
    if (t + 1 < NT) stage(t + 1, cur ^ 1);

    const char* Kb = smem + cur * 32768;
    const char* Vb = Kb + 16384;

    // ---- QK^T (swapped): St[ks], rows=k (ks*32+l31), cols=q (l31) ---------
    f32x16 St[2];
#pragma unroll
    for (int ks = 0; ks < 2; ks++)
#pragma unroll
      for (int r = 0; r < 16; r++) St[ks][r] = 0.f;
#pragma unroll
    for (int ks = 0; ks < 2; ks++) {
      int krow = ks * 32 + l31;        // (krow&15)==(l31&15)
#pragma unroll
      for (int dc = 0; dc < 8; dc++) {
        bf16x8 kf = *reinterpret_cast<const bf16x8*>(
            Kb + (size_t)krow * 256 + ((dc * 32 + h * 16) ^ swl16));
        St[ks] = MFMA32(kf, qa[dc], St[ks]);
      }
    }

    // ---- online softmax (per q = lane col) + in-register P packing --------
    // tree max over the 32 in-lane values
    f32x16 mm;
#pragma unroll
    for (int r = 0; r < 16; r++) mm[r] = fmaxf(St[0][r], St[1][r]);
#pragma unroll
    for (int st = 8; st; st >>= 1)
#pragma unroll
      for (int r = 0; r < 8; r++)
        if (r < st) mm[r] = fmaxf(mm[r], mm[r + st]);
    float pm = red32_max(mm[0]);
    float pms = pm * k2;
    if (__any(pms > msc + 8.f)) {      // defer-max (T13)
      float nm = fmaxf(msc, pms);
      float al = __builtin_amdgcn_exp2f(msc - nm);
      msc = nm;
      lsum *= al;
#pragma unroll
      for (int cb = 0; cb < 4; cb++)
#pragma unroll
        for (int r = 0; r < 16; r++) O[cb][r] *= al;
    }
    float p[2][16];
#pragma unroll
    for (int ks = 0; ks < 2; ks++)
#pragma unroll
      for (int r = 0; r < 16; r++)
        p[ks][r] = __builtin_amdgcn_exp2f(St[ks][r] * k2 - msc);
    // tree sum
    f32x16 sm;
#pragma unroll
    for (int r = 0; r < 16; r++) sm[r] = p[0][r] + p[1][r];
#pragma unroll
    for (int st = 8; st; st >>= 1)
#pragma unroll
      for (int r = 0; r < 8; r++)
        if (r < st) sm[r] = sm[r] + sm[r + st];
    lsum += red32_sum(sm[0]);
    // pack to PV B-frags (permlane32_swap: one swap fills two output words)
    u32x4 pk[2][2];  // [ks][kc]
#pragma unroll
    for (int ks = 0; ks < 2; ks++) {
#pragma unroll
      for (int kc = 0; kc < 2; kc++) {
        int bs = kc * 8;
        unsigned int a0 = pkbf(p[ks][bs + 0], p[ks][bs + 1]);
        unsigned int a1 = pkbf(p[ks][bs + 2], p[ks][bs + 3]);
        unsigned int b0 = pkbf(p[ks][bs + 4], p[ks][bs + 5]);
        unsigned int b1 = pkbf(p[ks][bs + 6], p[ks][bs + 7]);
        lane32_swap(a0, b0);   // a0 -> pv[0], b0 -> pv[2]
        lane32_swap(a1, b1);   // a1 -> pv[1], b1 -> pv[3]
        u32x4 pv;
        pv[0] = a0; pv[1] = a1; pv[2] = b0; pv[3] = b1;
        pk[ks][kc] = pv;
      }
    }

    // ---- PV: O^T[c][q] += V^T-frag x P-frag --------------------------------
#pragma unroll
    for (int ks = 0; ks < 2; ks++) {
#pragma unroll
      for (int kc = 0; kc < 2; kc++) {
#pragma unroll
        for (int cb = 0; cb < 4; cb++) {
          int vrow = (cb & 1) * 32 + l31;            // (vrow&15)==(l31&15)
          int lcol = ((cb >> 1) << 7) + ks * 64 + kc * 32 + h * 16;
          bf16x8 vf = *reinterpret_cast<const bf16x8*>(
              Vb + (size_t)vrow * 256 + (lcol ^ swl16));
          O[cb] = MFMA32(vf, __builtin_bit_cast(bf16x8, pk[ks][kc]), O[cb]);
        }
      }
    }
    cur ^= 1;
  }

  // ---- epilogue: write unnormalized partial O^T (bf16) + (m, l) ------------
  __bf16* po = (kq == 0) ? po0 : (kq == 1) ? po1 : (kq == 2) ? po2 : po3;
  int qg = b * 8192 + qgrp * 128 + w * 32 + l31;
#pragma unroll
  for (int cb = 0; cb < 4; cb++) {
#pragma unroll
    for (int rq = 0; rq < 4; rq++) {
      int c = cb * 32 + rq * 8 + h * 4;
      u32x2 wv;
      wv[0] = pkbf(O[cb][rq * 4 + 0], O[cb][rq * 4 + 1]);
      wv[1] = pkbf(O[cb][rq * 4 + 2], O[cb][rq * 4 + 3]);
      *reinterpret_cast<u32x2*>((char*)po + ((size_t)qg * 128 + c) * 2) = wv;
    }
  }
  if (l < 32) {
    f32x2 v; v.x = msc; v.y = lsum;
    ml[(size_t)kq * 16384 + qg] = v;
  }
}

// ---------------- K5b: merge the four k-quarters -----------------------------
__global__ __launch_bounds__(256) void merge4_k(__bf16* __restrict__ po0,
                                                const __bf16* __restrict__ po1,
                                                const __bf16* __restrict__ po2,
                                                const __bf16* __restrict__ po3,
                                                const f32x2* __restrict__ ml) {
  int t = blockIdx.x * 256 + threadIdx.x;   // 65536 threads
  int qg = t >> 2;
  int c0 = (t & 3) * 32;
  f32x2 a0 = ml[qg], a1 = ml[16384 + qg], a2 = ml[32768 + qg], a3 = ml[49152 + qg];
  float M = fmaxf(fmaxf(a0.x, a1.x), fmaxf(a2.x, a3.x));
  float e0 = __builtin_amdgcn_exp2f(a0.x - M);
  float e1 = __builtin_amdgcn_exp2f(a1.x - M);
  float e2 = __builtin_amdgcn_exp2f(a2.x - M);
  float e3 = __builtin_amdgcn_exp2f(a3.x - M);
  float L = e0 * a0.y + e1 * a1.y + e2 * a2.y + e3 * a3.y;
  float invL = 1.f / L;
  float c0f = e0 * invL, c1f = e1 * invL, c2f = e2 * invL, c3f = e3 * invL;
#pragma unroll
  for (int j = 0; j < 4; j++) {
    size_t off = (size_t)qg * 128 + c0 + j * 8;
    bf16x8 v0 = *reinterpret_cast<const bf16x8*>(&po0[off]);
    bf16x8 v1 = *reinterpret_cast<const bf16x8*>(&po1[off]);
    bf16x8 v2 = *reinterpret_cast<const bf16x8*>(&po2[off]);
    bf16x8 v3 = *reinterpret_cast<const bf16x8*>(&po3[off]);
    bf16x8 o;
#pragma unroll
    for (int i = 0; i < 8; i++)
      o[i] = (__bf16)(c0f * (float)v0[i] + c1f * (float)v1[i] +
                      c2f * (float)v2[i] + c3f * (float)v3[i]);
    *reinterpret_cast<bf16x8*>(&po0[off]) = o;
  }
}

// ---------------- K6: proj GEMM + bias + residual ----------------------------
__global__ __launch_bounds__(256) void proj_k(const __bf16* __restrict__ h,
                                              const __bf16* __restrict__ wp,
                                              const float* __restrict__ b_proj,
                                              const float* __restrict__ x,
                                              float* __restrict__ out) {
  int id = blockIdx.x;            // 2 * 2 * 128
  int b = id >> 8;
  int co0 = ((id >> 7) & 1) * 64;
  int n0 = (id & 127) * 64;
  int w = threadIdx.x >> 6, l = threadIdx.x & 63;
  int lr = l & 15, lh = l >> 4;
  int cow = co0 + w * 16;

  bf16x8 a[4];
#pragma unroll
  for (int kc = 0; kc < 4; kc++)
    a[kc] = *reinterpret_cast<const bf16x8*>(&wp[(size_t)(cow + lr) * 128 + kc * 32 + lh * 8]);

  const __bf16* hb = h + (size_t)b * Nvox * Cch;
#pragma unroll
  for (int ns = 0; ns < 4; ns++) {
    f32x4 acc = {0.f, 0.f, 0.f, 0.f};
#pragma unroll
    for (int kc = 0; kc < 4; kc++) {
      bf16x8 bf = *reinterpret_cast<const bf16x8*>(
          &hb[(size_t)(n0 + ns * 16 + lr) * Cch + kc * 32 + lh * 8]);
      acc = MFMA16(a[kc], bf, acc);
    }
#pragma unroll
    for (int r2 = 0; r2 < 4; r2++) {
      int co = cow + lh * 4 + r2;
      int n = n0 + ns * 16 + lr;
      size_t idx = ((size_t)b * Cch + co) * Nvox + n;
      out[idx] = x[idx] + b_proj[co] + acc[r2];
    }
  }
}

extern "C" void kernel_launch(void* const* d_in, const int* in_sizes, int n_in,
                              void* d_out, int out_size, void* d_ws, size_t ws_size,
                              hipStream_t stream) {
  const float* x      = (const float*)d_in[0];
  const float* gamma  = (const float*)d_in[1];
  const float* beta   = (const float*)d_in[2];
  const float* w_qkv  = (const float*)d_in[3];
  const float* b_qkv  = (const float*)d_in[4];
  const float* w_proj = (const float*)d_in[5];
  const float* b_proj = (const float*)d_in[6];
  float* out = (float*)d_out;

  char* ws = (char*)d_ws;
  float*  stats = (float*)ws;                      // 128 B
  f32x2*  part  = (f32x2*)(ws + 256);              // 2 KB
  __bf16* wq_b  = (__bf16*)(ws + 4096);            // 98304 B
  __bf16* wp_b  = (__bf16*)(ws + 4096 + 98304);    // 32768 B
  size_t base = 135168;
  const size_t SZ = (size_t)2 * Nvox * Cch * sizeof(__bf16); // 4 MiB
  __bf16* xn  = (__bf16*)(ws + base + 0 * SZ);     // reused as po1
  __bf16* qw  = (__bf16*)(ws + base + 1 * SZ);
  __bf16* kw  = (__bf16*)(ws + base + 2 * SZ);
  __bf16* vtw = (__bf16*)(ws + base + 3 * SZ);
  __bf16* hw  = (__bf16*)(ws + base + 4 * SZ);     // po0, then merged h
  f32x2*  ml  = (f32x2*)(ws + base + 5 * SZ);      // 512 KB
  __bf16* po2 = (__bf16*)(ws + base + 5 * SZ + 524288);
  __bf16* po3 = (__bf16*)(ws + base + 5 * SZ + 524288 + SZ);
  // total ws use: ~30 MB

  (void)hipFuncSetAttribute((const void*)attn_k,
                            hipFuncAttributeMaxDynamicSharedMemorySize, 65536);

  gn_part_k<<<256, 256, 0, stream>>>(x, part);
  gn_fin_k<<<1, 256, 0, stream>>>(part, stats);
  conv_w_k<<<192, 256, 0, stream>>>(w_qkv, w_proj, wq_b, wp_b);
  gn_apply_k<<<256, 256, 0, stream>>>(x, gamma, beta, stats, xn);
  qkv_k<<<1536, 256, 0, stream>>>(xn, wq_b, b_qkv, qw, kw, vtw);
  attn_k<<<512, 256, 65536, stream>>>(qw, kw, vtw, hw, xn, po2, po3, ml);
  merge4_k<<<256, 256, 0, stream>>>(hw, xn, po2, po3, ml);
  proj_k<<<512, 256, 0, stream>>>(hw, wp_b, b_proj, x, out);
}